// Round 10
// baseline (289.803 us; speedup 1.0000x reference)
//
#include <hip/hip_runtime.h>
#include <hip/hip_bf16.h>
#include <math.h>

// ---------------------------------------------------------------------------
// RGCN forward. ALL activations as single-plane bf16 rows (256B/row);
// weights split-bf16 (hi/lo) in MFMA fragment order -> 2 MFMA per frag.
// conv1: x->bf16, fused add-gather, one K=512 GEMM + LN1 + relu.
// conv2: ONE multi-head GEMM (x1 staged once, 4 accumulator sets in
//        registers, bf16 outputs incl. acc, 2 store-drain epilogue),
//        then ONE fused maxagg+LN2+relu+resid pass.
// classifier: gemm+LN+gelu x2, gemm40+log_softmax fused.
// All global stores are full-line contiguous (LDS-staged epilogues).
// ---------------------------------------------------------------------------

typedef __attribute__((ext_vector_type(8))) short bf16x8;
typedef __attribute__((ext_vector_type(4))) float f32x4;
typedef unsigned short ushort_t;

__device__ __forceinline__ ushort_t bf16rne(float v) {
    unsigned u = __float_as_uint(v);
    return (ushort_t)((u + 0x7FFFu + ((u >> 16) & 1u)) >> 16);
}

__device__ __forceinline__ void split_bf16(float v, ushort_t& h, ushort_t& l) {
    ushort_t hu = bf16rne(v);
    float hf = __uint_as_float((unsigned)hu << 16);
    h = hu;
    l = bf16rne(v - hf);
}

__device__ __forceinline__ float bf2f(unsigned u16) {
    return __uint_as_float(u16 << 16);
}

__device__ __forceinline__ float4 unpack_bf4(uint2 u) {
    return make_float4(bf2f(u.x & 0xFFFFu), bf2f(u.x >> 16),
                       bf2f(u.y & 0xFFFFu), bf2f(u.y >> 16));
}

__device__ __forceinline__ uint2 pack_bf4(float4 v) {
    uint2 o;
    o.x = (unsigned)bf16rne(v.x) | ((unsigned)bf16rne(v.y) << 16);
    o.y = (unsigned)bf16rne(v.z) | ((unsigned)bf16rne(v.w) << 16);
    return o;
}

// ================= convert ALL weights to fragment order (1 launch) ========
// frag layout (ushort): [plane][ks 0..3][cf][lane 0..63][8], slot=32768 ush.
__device__ __forceinline__ void conv_body128(const float* __restrict__ W,
                                             ushort_t* __restrict__ out,
                                             int idx) {
    constexpr int NCF = 8;
    constexpr size_t PST = (size_t)4 * NCF * 512;
    int l = idx & 63;
    int cf = (idx >> 6) & 7;
    int ks = idx >> 9;
    int col = cf * 16 + (l & 15);
    int k0 = ks * 32 + (l >> 4) * 8;
    size_t base = (((size_t)ks * NCF + cf) * 64 + l) * 8;
#pragma unroll
    for (int j = 0; j < 8; ++j) {
        ushort_t h, lo_;
        split_bf16(W[(size_t)(k0 + j) * 128 + col], h, lo_);
        out[base + j] = h;
        out[PST + base + j] = lo_;
    }
}

__global__ __launch_bounds__(256) void convert_all(
    const float* __restrict__ w1_root, const float* __restrict__ w1_rel,
    const float* __restrict__ w2_root, const float* __restrict__ w2_rel,
    const float* __restrict__ cw1, const float* __restrict__ cw2,
    ushort_t* __restrict__ wfb) {
    int b = blockIdx.x;
    if (b < 72) {
        const float* src;
        int slot;
        if (b < 8)       { slot = 0;              src = w1_root; }
        else if (b < 32) { int r = (b - 8) >> 3;  slot = 1 + r; src = w1_rel + (size_t)r * 16384; }
        else if (b < 40) { slot = 4;              src = w2_root; }
        else if (b < 64) { int r = (b - 40) >> 3; slot = 5 + r; src = w2_rel + (size_t)r * 16384; }
        else             { slot = 8;              src = cw1; }
        int lb = (b < 8) ? b : (b < 32) ? ((b - 8) & 7) : (b < 40) ? (b - 32)
               : (b < 64) ? ((b - 40) & 7) : (b - 64);
        conv_body128(src, wfb + (size_t)slot * 32768, lb * 256 + threadIdx.x);
    } else {
        // slot 9: cw2 K=128 x NCOL=64
        constexpr int NCF = 4;
        constexpr size_t PST = (size_t)4 * NCF * 512;
        int idx = (b - 72) * 256 + threadIdx.x;   // 4096 items
        ushort_t* out = wfb + (size_t)9 * 32768;
        int l = idx & 63;
        int cf = (idx >> 6) & 3;
        int ks = idx >> 8;
        int col = cf * 16 + (l & 15);
        int k0 = ks * 32 + (l >> 4) * 8;
        size_t base = (((size_t)ks * NCF + cf) * 64 + l) * 8;
#pragma unroll
        for (int j = 0; j < 8; ++j) {
            ushort_t h, lo_;
            split_bf16(cw2[(size_t)(k0 + j) * 64 + col], h, lo_);
            out[base + j] = h;
            out[PST + base + j] = lo_;
        }
    }
}

// ===================== x (f32) -> compact bf16 copy ========================
__global__ __launch_bounds__(256) void x2bf(const float* __restrict__ x,
                                            ushort_t* __restrict__ xh, int n4) {
    int g = blockIdx.x * 256 + threadIdx.x;
    if (g >= n4) return;
    float4 v = ((const float4*)x)[g];
    ((uint2*)xh)[g] = pack_bf4(v);
}

// ============= GEMM  Y[M,NCOL] = sum_s A_s[M,128] @ W_s + bias =============
// A_s: bf16 rows 256B. 256 thr / 4 waves (2x2), 64 rows/block.
// FUSE: 0 = bias, f32 out   1 = LN+relu, bf16 out   2 = LN+gelu, bf16 out
//       3 = LN+gelu, f32 out   4 = bias, bf16 out
template <int NCOL, int NSEG, int FUSE>
__global__ __launch_bounds__(256, 3) void gemm_bf(
    const ushort_t* __restrict__ A0, const ushort_t* __restrict__ A1,
    const ushort_t* __restrict__ A2, const ushort_t* __restrict__ A3,
    const ushort_t* __restrict__ wfrag, const float* __restrict__ bias,
    const float* __restrict__ lng, const float* __restrict__ lnb,
    void* __restrict__ Yv, int M) {
    constexpr int NCF = NCOL / 16;
    constexpr int WF = NCOL / 32;
    constexpr int PST = 4 * NCF * 512;
    constexpr int WSEG = 2 * PST;
    constexpr int RS = NCOL * 4 + 16;
    constexpr int EPB = 64 * RS;
    constexpr int SMEM_BYTES = (EPB > 16384) ? EPB : 16384;
    __shared__ __align__(16) char smem[SMEM_BYTES];
    char (*lds)[8192] = (char(*)[8192])smem;

    const int tid = threadIdx.x;
    const int wv = tid >> 6, lane = tid & 63, l15 = lane & 15, lg = lane >> 4;
    const int rowgrp = wv >> 1, colgrp = wv & 1;
    const int row0 = blockIdx.x * 64;
    const ushort_t* As[4] = {A0, A1, A2, A3};

    f32x4 acc[2][WF];
#pragma unroll
    for (int xf = 0; xf < 2; ++xf)
#pragma unroll
        for (int wf = 0; wf < WF; ++wf) acc[xf][wf] = (f32x4){0.f, 0.f, 0.f, 0.f};

    uint4 regs[2];

    auto LOADSTAGE = [&](int ch) {
        const ushort_t* __restrict__ A = As[ch >> 1];
        int kcb = (ch & 1) * 128;            // byte offset of k-chunk in row
#pragma unroll
        for (int i = 0; i < 2; ++i) {
            int s = tid + i * 256;           // 512 slots: 64r x 8 c16
            int r = s >> 3, c16 = s & 7;
            int gr = row0 + r;
            uint4 v = make_uint4(0u, 0u, 0u, 0u);
            if (gr < M)
                v = *(const uint4*)((const char*)A + (size_t)gr * 256 + kcb + c16 * 16);
            regs[i] = v;
        }
    };

    auto WRITESTAGE = [&](int buf) {
        char* L = lds[buf];
#pragma unroll
        for (int i = 0; i < 2; ++i) {
            int s = tid + i * 256;
            int r = s >> 3, c16 = s & 7;
            int byte = (r * 128 + c16 * 16) ^ ((r & 7) << 4);
            *(uint4*)(L + byte) = regs[i];
        }
    };

    auto COMPUTE = [&](int ch, int buf) {
        int seg = ch >> 1, half = ch & 1;
        const ushort_t* __restrict__ ws = wfrag + (size_t)seg * WSEG;
        const char* L = lds[buf];
#pragma unroll
        for (int kk = 0; kk < 2; ++kk) {
            int ks = half * 2 + kk;
            bf16x8 xh[2];
#pragma unroll
            for (int xf = 0; xf < 2; ++xf) {
                int r = rowgrp * 32 + xf * 16 + l15;
                int byte = (r * 128 + kk * 64 + lg * 16) ^ ((r & 7) << 4);
                xh[xf] = *(const bf16x8*)(L + byte);
            }
            bf16x8 wh[WF], wl[WF];
#pragma unroll
            for (int wf = 0; wf < WF; ++wf) {
                size_t off = (((size_t)ks * NCF + colgrp * WF + wf) * 64 + lane) * 8;
                wh[wf] = *(const bf16x8*)(ws + off);
                wl[wf] = *(const bf16x8*)(ws + PST + off);
            }
#pragma unroll
            for (int xf = 0; xf < 2; ++xf)
#pragma unroll
                for (int wf = 0; wf < WF; ++wf) {
                    acc[xf][wf] = __builtin_amdgcn_mfma_f32_16x16x32_bf16(
                        wh[wf], xh[xf], acc[xf][wf], 0, 0, 0);
                    acc[xf][wf] = __builtin_amdgcn_mfma_f32_16x16x32_bf16(
                        wl[wf], xh[xf], acc[xf][wf], 0, 0, 0);
                }
        }
    };

    constexpr int CH = 2 * NSEG;
    LOADSTAGE(0);
    WRITESTAGE(0);
    __syncthreads();
    for (int ch = 0; ch < CH; ++ch) {
        if (ch + 1 < CH) LOADSTAGE(ch + 1);
        COMPUTE(ch, ch & 1);
        __syncthreads();
        if (ch + 1 < CH) WRITESTAGE((ch + 1) & 1);
        __syncthreads();
    }

    // ---- stage acc tile (+bias) into LDS as full f32 rows ----
    {
        float4 bv[WF];
#pragma unroll
        for (int wf = 0; wf < WF; ++wf) {
            int col = colgrp * (NCOL / 2) + wf * 16 + lg * 4;
            bv[wf] = bias ? *(const float4*)(bias + col)
                          : make_float4(0.f, 0.f, 0.f, 0.f);
        }
#pragma unroll
        for (int xf = 0; xf < 2; ++xf) {
            int r = rowgrp * 32 + xf * 16 + l15;
#pragma unroll
            for (int wf = 0; wf < WF; ++wf) {
                int col = colgrp * (NCOL / 2) + wf * 16 + lg * 4;
                float4 o;
                o.x = acc[xf][wf][0] + bv[wf].x;
                o.y = acc[xf][wf][1] + bv[wf].y;
                o.z = acc[xf][wf][2] + bv[wf].z;
                o.w = acc[xf][wf][3] + bv[wf].w;
                *(float4*)(smem + r * RS + col * 4) = o;
            }
        }
    }
    __syncthreads();

    if (FUSE >= 1 && FUSE <= 3) {
        constexpr int CPT = NCOL / 4;
        int r = tid >> 2, seg = tid & 3;
        char* rp = smem + r * RS + seg * CPT * 4;
        float s = 0.f, sq = 0.f;
        float4 vv[CPT / 4];
#pragma unroll
        for (int j = 0; j < CPT / 4; ++j) {
            float4 v = *(const float4*)(rp + j * 16);
            vv[j] = v;
            s += (v.x + v.y) + (v.z + v.w);
            sq += (v.x * v.x + v.y * v.y) + (v.z * v.z + v.w * v.w);
        }
        s += __shfl_xor(s, 1, 64); sq += __shfl_xor(sq, 1, 64);
        s += __shfl_xor(s, 2, 64); sq += __shfl_xor(sq, 2, 64);
        float mu = s * (1.f / NCOL);
        float var = sq * (1.f / NCOL) - mu * mu;
        float rstd = rsqrtf(var + 1e-5f);
#pragma unroll
        for (int j = 0; j < CPT / 4; ++j) {
            int c0 = seg * CPT + j * 4;
            float4 v = vv[j];
            float4 gg = *(const float4*)(lng + c0);
            float4 bb = *(const float4*)(lnb + c0);
            float y0 = (v.x - mu) * rstd * gg.x + bb.x;
            float y1 = (v.y - mu) * rstd * gg.y + bb.y;
            float y2 = (v.z - mu) * rstd * gg.z + bb.z;
            float y3 = (v.w - mu) * rstd * gg.w + bb.w;
            if (FUSE == 1) {
                y0 = fmaxf(y0, 0.f); y1 = fmaxf(y1, 0.f);
                y2 = fmaxf(y2, 0.f); y3 = fmaxf(y3, 0.f);
            } else {
                y0 = 0.5f * y0 * (1.f + erff(y0 * 0.70710678118654752f));
                y1 = 0.5f * y1 * (1.f + erff(y1 * 0.70710678118654752f));
                y2 = 0.5f * y2 * (1.f + erff(y2 * 0.70710678118654752f));
                y3 = 0.5f * y3 * (1.f + erff(y3 * 0.70710678118654752f));
            }
            vv[j] = make_float4(y0, y1, y2, y3);
        }
        __syncthreads();
        if (FUSE == 3) {
#pragma unroll
            for (int j = 0; j < CPT / 4; ++j) *(float4*)(rp + j * 16) = vv[j];
        } else {
            // bf16 row region: first NCOL*2 bytes at base r*RS
#pragma unroll
            for (int j = 0; j < CPT / 4; ++j) {
                int c0 = seg * CPT + j * 4;
                *(uint2*)(smem + r * RS + 2 * c0) = pack_bf4(vv[j]);
            }
        }
        __syncthreads();
    }

    // ---- contiguous copy-out ----
    if (FUSE == 4) {
        constexpr int SL = 64 * (NCOL / 8);    // uint4 slots (bf16 rows)
#pragma unroll
        for (int i = 0; i < SL / 256; ++i) {
            int slot = tid + i * 256;
            int rr = slot / (NCOL / 8), c16 = slot % (NCOL / 8);
            int gr = row0 + rr;
            if (gr < M) {
                float4 a = *(const float4*)(smem + rr * RS + c16 * 32);
                float4 b = *(const float4*)(smem + rr * RS + c16 * 32 + 16);
                uint4 o;
                uint2 pa = pack_bf4(a), pb = pack_bf4(b);
                o.x = pa.x; o.y = pa.y; o.z = pb.x; o.w = pb.y;
                *(uint4*)((char*)Yv + (size_t)gr * (NCOL * 2) + c16 * 16) = o;
            }
        }
    } else {
        constexpr int OUTB = (FUSE == 0 || FUSE == 3) ? NCOL * 4 : NCOL * 2;
        constexpr int RP = OUTB / 16;
        constexpr int SL = 64 * RP;
#pragma unroll
        for (int i = 0; i < SL / 256; ++i) {
            int slot = tid + i * 256;
            int rr = slot / RP, c16 = slot % RP;
            int gr = row0 + rr;
            if (gr < M)
                *(uint4*)((char*)Yv + (size_t)gr * OUTB + c16 * 16) =
                    *(const uint4*)(smem + rr * RS + c16 * 16);
        }
    }
}

// ======== conv2 multi-head GEMM: x1 staged once, 4 reg accumulator sets ====
// set 0 -> acc bf16 (+b2); sets 1-3 -> H_r bf16 rows. 2 store-drain epilogue.
__global__ __launch_bounds__(256, 2) void gemm_conv2(
    const ushort_t* __restrict__ X, const ushort_t* __restrict__ wfb,
    const float* __restrict__ b2, ushort_t* __restrict__ ACbf,
    ushort_t* __restrict__ H0, ushort_t* __restrict__ H1,
    ushort_t* __restrict__ H2, int M) {
    constexpr int NCF = 8, WF = 4;
    constexpr int PST = 4 * NCF * 512;
    constexpr int RS2 = 256 + 16;                 // bf16 epilogue row stride
    __shared__ __align__(16) char smem[2 * 64 * RS2];   // 34816; Xs = first 16KB
    char* Xs = smem;

    const int tid = threadIdx.x;
    const int wv = tid >> 6, lane = tid & 63, l15 = lane & 15, lg = lane >> 4;
    const int rowgrp = wv >> 1, colgrp = wv & 1;
    const int row0 = blockIdx.x * 64;

    // stage full X tile [64r][128k] bf16, swizzled
#pragma unroll
    for (int i = 0; i < 4; ++i) {
        int s = tid + i * 256;               // 1024 slots
        int r = s >> 4, c16 = s & 15;
        int gr = row0 + r;
        uint4 v = make_uint4(0u, 0u, 0u, 0u);
        if (gr < M) v = *(const uint4*)((const char*)X + (size_t)gr * 256 + c16 * 16);
        int byte = (r * 256 + c16 * 16) ^ ((r & 7) << 4);
        *(uint4*)(Xs + byte) = v;
    }
    __syncthreads();

    f32x4 acc[4][2][WF];
#pragma unroll
    for (int set = 0; set < 4; ++set)
#pragma unroll
        for (int xf = 0; xf < 2; ++xf)
#pragma unroll
            for (int wf = 0; wf < WF; ++wf)
                acc[set][xf][wf] = (f32x4){0.f, 0.f, 0.f, 0.f};

#pragma unroll
    for (int ks = 0; ks < 4; ++ks) {
        bf16x8 xh[2];
#pragma unroll
        for (int xf = 0; xf < 2; ++xf) {
            int r = rowgrp * 32 + xf * 16 + l15;
            int byte = (r * 256 + ks * 64 + lg * 16) ^ ((r & 7) << 4);
            xh[xf] = *(const bf16x8*)(Xs + byte);
        }
#pragma unroll
        for (int set = 0; set < 4; ++set) {
            const ushort_t* __restrict__ ws = wfb + (size_t)(4 + set) * 32768;
            bf16x8 wh[WF], wl[WF];
#pragma unroll
            for (int wf = 0; wf < WF; ++wf) {
                size_t off = (((size_t)ks * NCF + colgrp * WF + wf) * 64 + lane) * 8;
                wh[wf] = *(const bf16x8*)(ws + off);
                wl[wf] = *(const bf16x8*)(ws + PST + off);
            }
#pragma unroll
            for (int xf = 0; xf < 2; ++xf)
#pragma unroll
                for (int wf = 0; wf < WF; ++wf) {
                    acc[set][xf][wf] = __builtin_amdgcn_mfma_f32_16x16x32_bf16(
                        wh[wf], xh[xf], acc[set][xf][wf], 0, 0, 0);
                    acc[set][xf][wf] = __builtin_amdgcn_mfma_f32_16x16x32_bf16(
                        wl[wf], xh[xf], acc[set][xf][wf], 0, 0, 0);
                }
        }
    }
    __syncthreads();   // all Xs reads done; LDS reusable as epilogue tiles

    ushort_t* outs[4] = {ACbf, H0, H1, H2};
#pragma unroll
    for (int round = 0; round < 2; ++round) {
        // stage two bf16 tiles
#pragma unroll
        for (int s2 = 0; s2 < 2; ++s2) {
            int set = round * 2 + s2;
            char* tile = smem + s2 * (64 * RS2);
#pragma unroll
            for (int xf = 0; xf < 2; ++xf) {
                int r = rowgrp * 32 + xf * 16 + l15;
#pragma unroll
                for (int wf = 0; wf < WF; ++wf) {
                    int col = colgrp * 64 + wf * 16 + lg * 4;
                    float4 o;
                    o.x = acc[set][xf][wf][0];
                    o.y = acc[set][xf][wf][1];
                    o.z = acc[set][xf][wf][2];
                    o.w = acc[set][xf][wf][3];
                    if (set == 0) {
                        float4 bv = *(const float4*)(b2 + col);
                        o.x += bv.x; o.y += bv.y; o.z += bv.z; o.w += bv.w;
                    }
                    *(uint2*)(tile + r * RS2 + col * 2) = pack_bf4(o);
                }
            }
        }
        __syncthreads();
        // contiguous copy-out of both tiles (full 256B rows)
#pragma unroll
        for (int s2 = 0; s2 < 2; ++s2) {
            int set = round * 2 + s2;
            ushort_t* O = outs[set];
            const char* tile = smem + s2 * (64 * RS2);
#pragma unroll
            for (int i = 0; i < 4; ++i) {
                int slot = tid + i * 256;    // 1024: 64r x 16 c16
                int rr = slot >> 4, c16 = slot & 15;
                int gr = row0 + rr;
                if (gr < M)
                    *(uint4*)((char*)O + (size_t)gr * 256 + c16 * 16) =
                        *(const uint4*)(tile + rr * RS2 + c16 * 16);
            }
        }
        if (round == 0) __syncthreads();
    }
}

// ============================== CSR build ((dst,rel)-sorted) ===============
__global__ __launch_bounds__(256) void hist3_kernel(const int* __restrict__ edst,
                                                    const int* __restrict__ etype,
                                                    int* __restrict__ deg3, int E) {
    int e = blockIdx.x * 256 + threadIdx.x;
    if (e < E) atomicAdd(&deg3[edst[e] * 3 + etype[e]], 1);
}

__global__ __launch_bounds__(256) void degtot_kernel(const int* __restrict__ deg3,
                                                     int* __restrict__ degtot, int N) {
    int n = blockIdx.x * 256 + threadIdx.x;
    if (n < N) degtot[n] = deg3[n * 3] + deg3[n * 3 + 1] + deg3[n * 3 + 2];
}

__global__ __launch_bounds__(256) void scan_block(const int* __restrict__ in,
                                                  int* __restrict__ out,
                                                  int* __restrict__ sums, int n) {
    __shared__ int s[256];
    int g = blockIdx.x * 256 + threadIdx.x;
    int v = (g < n) ? in[g] : 0;
    s[threadIdx.x] = v;
    __syncthreads();
    int acc = v;
    for (int off = 1; off < 256; off <<= 1) {
        int t = (threadIdx.x >= off) ? s[threadIdx.x - off] : 0;
        __syncthreads();
        acc += t;
        s[threadIdx.x] = acc;
        __syncthreads();
    }
    if (g < n) out[g] = acc - v;
    if (threadIdx.x == 255 && sums) sums[blockIdx.x] = acc;
}

__global__ __launch_bounds__(256) void scan_add(int* __restrict__ out,
                                                const int* __restrict__ topex,
                                                int n, int total) {
    int g = blockIdx.x * 256 + threadIdx.x;
    if (g < n) out[g] += topex[blockIdx.x];
    if (g == 0) out[n] = total;
}

__global__ __launch_bounds__(256) void ranges_kernel(
    const int* __restrict__ rowptr, const int* __restrict__ deg3,
    int4* __restrict__ ranges, int* __restrict__ cursor3, int N) {
    int n = blockIdx.x * 256 + threadIdx.x;
    if (n >= N) return;
    int b = rowptr[n];
    int d0 = deg3[n * 3], d1 = deg3[n * 3 + 1];
    int4 r;
    r.x = b; r.y = b + d0; r.z = b + d0 + d1; r.w = rowptr[n + 1];
    ranges[n] = r;
    cursor3[n * 3] = r.x; cursor3[n * 3 + 1] = r.y; cursor3[n * 3 + 2] = r.z;
}

__global__ __launch_bounds__(256) void fill3_kernel(
    const int* __restrict__ esrc, const int* __restrict__ edst,
    const int* __restrict__ etype, int* __restrict__ cursor3,
    int* __restrict__ colidx, int E) {
    int e = blockIdx.x * 256 + threadIdx.x;
    if (e >= E) return;
    int pos = atomicAdd(&cursor3[edst[e] * 3 + etype[e]], 1);
    colidx[pos] = esrc[e];
}

// ========== fused add-gather from bf16 x -> bf16 S rows ====================
__device__ __forceinline__ float4 gather_sum_bf(const ushort_t* __restrict__ XH,
                                                const int* __restrict__ colidx,
                                                int beg, int end, int l) {
    float4 a = make_float4(0.f, 0.f, 0.f, 0.f);
    int e = beg;
    for (; e + 4 <= end; e += 4) {
        int s0 = colidx[e], s1 = colidx[e + 1];
        int s2 = colidx[e + 2], s3 = colidx[e + 3];
        float4 v0 = unpack_bf4(*(const uint2*)(XH + (size_t)s0 * 128 + l * 4));
        float4 v1 = unpack_bf4(*(const uint2*)(XH + (size_t)s1 * 128 + l * 4));
        float4 v2 = unpack_bf4(*(const uint2*)(XH + (size_t)s2 * 128 + l * 4));
        float4 v3 = unpack_bf4(*(const uint2*)(XH + (size_t)s3 * 128 + l * 4));
        a.x += (v0.x + v1.x) + (v2.x + v3.x);
        a.y += (v0.y + v1.y) + (v2.y + v3.y);
        a.z += (v0.z + v1.z) + (v2.z + v3.z);
        a.w += (v0.w + v1.w) + (v2.w + v3.w);
    }
    for (; e < end; ++e) {
        float4 v = unpack_bf4(*(const uint2*)(XH + (size_t)colidx[e] * 128 + l * 4));
        a.x += v.x; a.y += v.y; a.z += v.z; a.w += v.w;
    }
    return a;
}

__global__ __launch_bounds__(256) void agg3_add(
    const ushort_t* __restrict__ xh, const int4* __restrict__ ranges,
    const int* __restrict__ colidx, ushort_t* __restrict__ S0,
    ushort_t* __restrict__ S1, ushort_t* __restrict__ S2, int N) {
    int node = blockIdx.x * 8 + (threadIdx.x >> 5);
    int l = threadIdx.x & 31;
    if (node >= N) return;
    int4 rg = ranges[node];
    float4 a0 = gather_sum_bf(xh, colidx, rg.x, rg.y, l);
    float4 a1 = gather_sum_bf(xh, colidx, rg.y, rg.z, l);
    float4 a2 = gather_sum_bf(xh, colidx, rg.z, rg.w, l);
    *(uint2*)(S0 + (size_t)node * 128 + l * 4) = pack_bf4(a0);
    *(uint2*)(S1 + (size_t)node * 128 + l * 4) = pack_bf4(a1);
    *(uint2*)(S2 + (size_t)node * 128 + l * 4) = pack_bf4(a2);
}

// ======= fused: acc(bf16) + sum_r max-gather(H_r bf16) -> LN -> relu+resid =
__device__ __forceinline__ float4 gather_max_bf(const ushort_t* __restrict__ H,
                                                const int* __restrict__ colidx,
                                                int beg, int end, int l) {
    float4 m = make_float4(-INFINITY, -INFINITY, -INFINITY, -INFINITY);
    int e = beg;
    for (; e + 4 <= end; e += 4) {
        int s0 = colidx[e], s1 = colidx[e + 1];
        int s2 = colidx[e + 2], s3 = colidx[e + 3];
        float4 v0 = unpack_bf4(*(const uint2*)(H + (size_t)s0 * 128 + l * 4));
        float4 v1 = unpack_bf4(*(const uint2*)(H + (size_t)s1 * 128 + l * 4));
        float4 v2 = unpack_bf4(*(const uint2*)(H + (size_t)s2 * 128 + l * 4));
        float4 v3 = unpack_bf4(*(const uint2*)(H + (size_t)s3 * 128 + l * 4));
        m.x = fmaxf(m.x, fmaxf(fmaxf(v0.x, v1.x), fmaxf(v2.x, v3.x)));
        m.y = fmaxf(m.y, fmaxf(fmaxf(v0.y, v1.y), fmaxf(v2.y, v3.y)));
        m.z = fmaxf(m.z, fmaxf(fmaxf(v0.z, v1.z), fmaxf(v2.z, v3.z)));
        m.w = fmaxf(m.w, fmaxf(fmaxf(v0.w, v1.w), fmaxf(v2.w, v3.w)));
    }
    for (; e < end; ++e) {
        float4 v = unpack_bf4(*(const uint2*)(H + (size_t)colidx[e] * 128 + l * 4));
        m.x = fmaxf(m.x, v.x); m.y = fmaxf(m.y, v.y);
        m.z = fmaxf(m.z, v.z); m.w = fmaxf(m.w, v.w);
    }
    m.x = (m.x > -3e38f) ? m.x : 0.f;
    m.y = (m.y > -3e38f) ? m.y : 0.f;
    m.z = (m.z > -3e38f) ? m.z : 0.f;
    m.w = (m.w > -3e38f) ? m.w : 0.f;
    return m;
}

__global__ __launch_bounds__(256) void maxagg_ln(
    const ushort_t* __restrict__ H0, const ushort_t* __restrict__ H1,
    const ushort_t* __restrict__ H2, const int4* __restrict__ ranges,
    const int* __restrict__ colidx, const ushort_t* __restrict__ accbf,
    const ushort_t* __restrict__ resid, const float* __restrict__ g,
    const float* __restrict__ b, ushort_t* __restrict__ outH, int N) {
    int node = blockIdx.x * 8 + (threadIdx.x >> 5);
    int l = threadIdx.x & 31;
    if (node >= N) return;
    int4 rg = ranges[node];
    float4 m0 = gather_max_bf(H0, colidx, rg.x, rg.y, l);
    float4 m1 = gather_max_bf(H1, colidx, rg.y, rg.z, l);
    float4 m2 = gather_max_bf(H2, colidx, rg.z, rg.w, l);
    float4 a = unpack_bf4(*(const uint2*)(accbf + (size_t)node * 128 + l * 4));
    a.x += m0.x + m1.x + m2.x;
    a.y += m0.y + m1.y + m2.y;
    a.z += m0.z + m1.z + m2.z;
    a.w += m0.w + m1.w + m2.w;
    float s = (a.x + a.y) + (a.z + a.w);
    float sq = (a.x * a.x + a.y * a.y) + (a.z * a.z + a.w * a.w);
#pragma unroll
    for (int off = 16; off; off >>= 1) {
        s += __shfl_xor(s, off, 64);
        sq += __shfl_xor(sq, off, 64);
    }
    float mu = s * (1.f / 128.f);
    float var = sq * (1.f / 128.f) - mu * mu;
    float rstd = rsqrtf(var + 1e-5f);
    float4 gg = *(const float4*)(g + l * 4);
    float4 bb = *(const float4*)(b + l * 4);
    float4 rv = unpack_bf4(*(const uint2*)(resid + (size_t)node * 128 + l * 4));
    float4 y;
    y.x = fmaxf((a.x - mu) * rstd * gg.x + bb.x, 0.f) + 0.2f * rv.x;
    y.y = fmaxf((a.y - mu) * rstd * gg.y + bb.y, 0.f) + 0.2f * rv.y;
    y.z = fmaxf((a.z - mu) * rstd * gg.z + bb.z, 0.f) + 0.2f * rv.z;
    y.w = fmaxf((a.w - mu) * rstd * gg.w + bb.w, 0.f) + 0.2f * rv.w;
    *(uint2*)(outH + (size_t)node * 128 + l * 4) = pack_bf4(y);
}

// ====== f32 GEMM  M x 64 @ 64 x 40 + bias + log_softmax -> out =============
__global__ __launch_bounds__(256) void gemm40_lsm(const float* __restrict__ X,
                                                  const float* __restrict__ W,
                                                  const float* __restrict__ bias,
                                                  float* __restrict__ Y, int M) {
    __shared__ float Xs[64][65];
    __shared__ float Ws[64 * 40];
    __shared__ float Ys[64][41];
    __shared__ float mx_[64], ls_[64];
    const int tid = threadIdx.x;
    const int row0 = blockIdx.x * 64;
    for (int i = tid; i < 64 * 40; i += 256) Ws[i] = W[i];
#pragma unroll
    for (int i = 0; i < 4; ++i) {
        int slot = tid + i * 256;
        int r = slot >> 4, c4 = slot & 15;
        float4 v = make_float4(0.f, 0.f, 0.f, 0.f);
        if (row0 + r < M) v = *(const float4*)(X + (size_t)(row0 + r) * 64 + c4 * 4);
        Xs[r][c4 * 4 + 0] = v.x; Xs[r][c4 * 4 + 1] = v.y;
        Xs[r][c4 * 4 + 2] = v.z; Xs[r][c4 * 4 + 3] = v.w;
    }
    __syncthreads();
    const int row = tid >> 2, cg = (tid & 3) * 10;
    float acc[10];
#pragma unroll
    for (int j = 0; j < 10; ++j) acc[j] = 0.f;
#pragma unroll 8
    for (int k = 0; k < 64; ++k) {
        float xv = Xs[row][k];
#pragma unroll
        for (int j = 0; j < 10; ++j) acc[j] = fmaf(xv, Ws[k * 40 + cg + j], acc[j]);
    }
#pragma unroll
    for (int j = 0; j < 10; ++j) Ys[row][cg + j] = acc[j] + bias[cg + j];
    __syncthreads();
    if (tid < 64) {
        float mx = -INFINITY;
#pragma unroll 8
        for (int c = 0; c < 40; ++c) mx = fmaxf(mx, Ys[tid][c]);
        float sum = 0.f;
#pragma unroll 8
        for (int c = 0; c < 40; ++c) sum += __expf(Ys[tid][c] - mx);
        mx_[tid] = mx;
        ls_[tid] = logf(sum);
    }
    __syncthreads();
#pragma unroll
    for (int i = 0; i < 10; ++i) {
        int slot = tid + i * 256;
        int r = slot / 40, c = slot % 40;
        int gr = row0 + r;
        if (gr < M) Y[(size_t)gr * 40 + c] = Ys[r][c] - mx_[r] - ls_[r];
    }
}

// ===========================================================================
extern "C" void kernel_launch(void* const* d_in, const int* in_sizes, int n_in,
                              void* d_out, int out_size, void* d_ws, size_t ws_size,
                              hipStream_t stream) {
    const float* x       = (const float*)d_in[0];
    const int*   eidx    = (const int*)d_in[1];
    const int*   etype   = (const int*)d_in[2];
    const float* w1_rel  = (const float*)d_in[3];
    const float* w1_root = (const float*)d_in[4];
    const float* b1      = (const float*)d_in[5];
    const float* ln1_g   = (const float*)d_in[6];
    const float* ln1_b   = (const float*)d_in[7];
    const float* w2_rel  = (const float*)d_in[8];
    const float* w2_root = (const float*)d_in[9];
    const float* b2      = (const float*)d_in[10];
    const float* ln2_g   = (const float*)d_in[11];
    const float* ln2_b   = (const float*)d_in[12];
    const float* cw1     = (const float*)d_in[13];
    const float* cb1     = (const float*)d_in[14];
    const float* cln1_g  = (const float*)d_in[15];
    const float* cln1_b  = (const float*)d_in[16];
    const float* cw2     = (const float*)d_in[17];
    const float* cb2     = (const float*)d_in[18];
    const float* cln2_g  = (const float*)d_in[19];
    const float* cln2_b  = (const float*)d_in[20];
    const float* cw3     = (const float*)d_in[21];
    const float* cb3     = (const float*)d_in[22];

    const int N = in_sizes[0] / 128;   // 50000
    const int E = in_sizes[1] / 2;     // 600000
    const int* esrc = eidx;
    const int* edst = eidx + E;

    const size_t HB = (size_t)N * 256;      // one bf16 [N,128] buffer, bytes
    char* base = (char*)d_ws;
    ushort_t* S0 = (ushort_t*)(base + 0 * HB);       // -> H0
    ushort_t* S1 = (ushort_t*)(base + 1 * HB);       // -> H1
    ushort_t* S2 = (ushort_t*)(base + 2 * HB);       // -> H2
    ushort_t* X1 = (ushort_t*)(base + 3 * HB);       // x1 bf16
    ushort_t* AC = (ushort_t*)(base + 4 * HB);       // acc2 bf16
    char*     B3 = base + 5 * HB;                    // META

    int* rowptr  = (int*)B3;                      // N+1
    int* degtot  = rowptr + (N + 1);              // N
    int* deg3    = degtot + N;                    // 3N
    int* cursor3 = deg3 + 3 * N;                  // 3N
    int* bsums   = cursor3 + 3 * N;               // 256
    int* btop    = bsums + 256;                   // 256
    int4* ranges = (int4*)(((uintptr_t)(btop + 256) + 15) & ~(uintptr_t)15);
    int* colidx  = (int*)(ranges + N);            // E
    ushort_t* wfb = (ushort_t*)(((uintptr_t)(colidx + E) + 255) & ~(uintptr_t)255);
    auto WSLOT = [&](int i) { return wfb + (size_t)i * 32768; };
    ushort_t* xh = (ushort_t*)(((uintptr_t)(wfb + 10 * 32768) + 255) & ~(uintptr_t)255);
    ushort_t* h2 = xh;                            // xh dead after conv1 gemm
    ushort_t* C1 = S0;                            // classifier temps reuse
    float*    C2 = (float*)S1;                    // [N,64] f32

    const dim3 blk(256);
    const int gGemm = (N + 63) / 64;
    const int gAgg  = (N + 7) / 8;
    const int gEdge = (E + 255) / 256;
    const int gNode = (N + 255) / 256;
    const int nScanB = (N + 255) / 256;
    const int gX2  = (N * 32 + 255) / 256;

    // ---------------- CSR build ----------------
    hipMemsetAsync(deg3, 0, (size_t)3 * N * sizeof(int), stream);
    hist3_kernel<<<gEdge, blk, 0, stream>>>(edst, etype, deg3, E);
    degtot_kernel<<<gNode, blk, 0, stream>>>(deg3, degtot, N);
    scan_block<<<nScanB, blk, 0, stream>>>(degtot, rowptr, bsums, N);
    scan_block<<<1, blk, 0, stream>>>(bsums, btop, nullptr, nScanB);
    scan_add<<<nScanB, blk, 0, stream>>>(rowptr, btop, N, E);
    ranges_kernel<<<gNode, blk, 0, stream>>>(rowptr, deg3, ranges, cursor3, N);
    fill3_kernel<<<gEdge, blk, 0, stream>>>(esrc, edst, etype, cursor3, colidx, E);

    // ---------------- weights + x conversion ----------------
    convert_all<<<76, blk, 0, stream>>>(w1_root, w1_rel, w2_root, w2_rel,
                                        cw1, cw2, wfb);
    x2bf<<<gX2, blk, 0, stream>>>(x, xh, N * 32);

    // ---------------- conv1 (add) ----------------
    agg3_add<<<gAgg, blk, 0, stream>>>(xh, ranges, colidx, S0, S1, S2, N);
    gemm_bf<128, 4, 1><<<gGemm, blk, 0, stream>>>(
        xh, S0, S1, S2, WSLOT(0), b1, ln1_g, ln1_b, X1, N);   // x1 bf16

    // ---------------- conv2 (max) ----------------
    gemm_conv2<<<gGemm, blk, 0, stream>>>(X1, wfb, b2, AC, S0, S1, S2, N);
    maxagg_ln<<<gAgg, blk, 0, stream>>>(S0, S1, S2, ranges, colidx, AC,
                                        X1, ln2_g, ln2_b, h2, N);

    // ---------------- classifier ----------------
    gemm_bf<128, 1, 2><<<gGemm, blk, 0, stream>>>(
        h2, h2, h2, h2, WSLOT(8), cb1, cln1_g, cln1_b, C1, N);   // bf16
    gemm_bf<64, 1, 3><<<gGemm, blk, 0, stream>>>(
        C1, C1, C1, C1, WSLOT(9), cb2, cln2_g, cln2_b, C2, N);   // f32 [N,64]
    gemm40_lsm<<<gGemm, blk, 0, stream>>>(C2, cw3, cb3, (float*)d_out, N);
}

// Round 11
// 266.890 us; speedup vs baseline: 1.0859x; 1.0859x over previous
//
#include <hip/hip_runtime.h>
#include <hip/hip_bf16.h>
#include <math.h>

// ---------------------------------------------------------------------------
// RGCN forward. ALL activations as single-plane bf16 rows (256B/row);
// weights split-bf16 (hi/lo) in MFMA fragment order -> 2 MFMA per frag.
// conv1: x->bf16, fused add-gather, one K=512 GEMM + LN1 + relu.
// conv2: ONE multi-head GEMM (x1 staged once; 4 weight sets SEQUENTIAL so
//        acc stays at 2xWF regs; bf16 epilogue tile; bf16 outputs incl acc),
//        then ONE fused maxagg+LN2+relu+resid pass.
// classifier: gemm+LN+gelu x2, gemm40+log_softmax fused.
// All global stores are full-line contiguous (LDS-staged epilogues).
// ---------------------------------------------------------------------------

typedef __attribute__((ext_vector_type(8))) short bf16x8;
typedef __attribute__((ext_vector_type(4))) float f32x4;
typedef unsigned short ushort_t;

__device__ __forceinline__ ushort_t bf16rne(float v) {
    unsigned u = __float_as_uint(v);
    return (ushort_t)((u + 0x7FFFu + ((u >> 16) & 1u)) >> 16);
}

__device__ __forceinline__ void split_bf16(float v, ushort_t& h, ushort_t& l) {
    ushort_t hu = bf16rne(v);
    float hf = __uint_as_float((unsigned)hu << 16);
    h = hu;
    l = bf16rne(v - hf);
}

__device__ __forceinline__ float bf2f(unsigned u16) {
    return __uint_as_float(u16 << 16);
}

__device__ __forceinline__ float4 unpack_bf4(uint2 u) {
    return make_float4(bf2f(u.x & 0xFFFFu), bf2f(u.x >> 16),
                       bf2f(u.y & 0xFFFFu), bf2f(u.y >> 16));
}

__device__ __forceinline__ uint2 pack_bf4(float4 v) {
    uint2 o;
    o.x = (unsigned)bf16rne(v.x) | ((unsigned)bf16rne(v.y) << 16);
    o.y = (unsigned)bf16rne(v.z) | ((unsigned)bf16rne(v.w) << 16);
    return o;
}

// ================= convert ALL weights to fragment order (1 launch) ========
// frag layout (ushort): [plane][ks 0..3][cf][lane 0..63][8], slot=32768 ush.
__device__ __forceinline__ void conv_body128(const float* __restrict__ W,
                                             ushort_t* __restrict__ out,
                                             int idx) {
    constexpr int NCF = 8;
    constexpr size_t PST = (size_t)4 * NCF * 512;
    int l = idx & 63;
    int cf = (idx >> 6) & 7;
    int ks = idx >> 9;
    int col = cf * 16 + (l & 15);
    int k0 = ks * 32 + (l >> 4) * 8;
    size_t base = (((size_t)ks * NCF + cf) * 64 + l) * 8;
#pragma unroll
    for (int j = 0; j < 8; ++j) {
        ushort_t h, lo_;
        split_bf16(W[(size_t)(k0 + j) * 128 + col], h, lo_);
        out[base + j] = h;
        out[PST + base + j] = lo_;
    }
}

__global__ __launch_bounds__(256) void convert_all(
    const float* __restrict__ w1_root, const float* __restrict__ w1_rel,
    const float* __restrict__ w2_root, const float* __restrict__ w2_rel,
    const float* __restrict__ cw1, const float* __restrict__ cw2,
    ushort_t* __restrict__ wfb) {
    int b = blockIdx.x;
    if (b < 72) {
        const float* src;
        int slot;
        if (b < 8)       { slot = 0;              src = w1_root; }
        else if (b < 32) { int r = (b - 8) >> 3;  slot = 1 + r; src = w1_rel + (size_t)r * 16384; }
        else if (b < 40) { slot = 4;              src = w2_root; }
        else if (b < 64) { int r = (b - 40) >> 3; slot = 5 + r; src = w2_rel + (size_t)r * 16384; }
        else             { slot = 8;              src = cw1; }
        int lb = (b < 8) ? b : (b < 32) ? ((b - 8) & 7) : (b < 40) ? (b - 32)
               : (b < 64) ? ((b - 40) & 7) : (b - 64);
        conv_body128(src, wfb + (size_t)slot * 32768, lb * 256 + threadIdx.x);
    } else {
        // slot 9: cw2 K=128 x NCOL=64
        constexpr int NCF = 4;
        constexpr size_t PST = (size_t)4 * NCF * 512;
        int idx = (b - 72) * 256 + threadIdx.x;   // 4096 items
        ushort_t* out = wfb + (size_t)9 * 32768;
        int l = idx & 63;
        int cf = (idx >> 6) & 3;
        int ks = idx >> 8;
        int col = cf * 16 + (l & 15);
        int k0 = ks * 32 + (l >> 4) * 8;
        size_t base = (((size_t)ks * NCF + cf) * 64 + l) * 8;
#pragma unroll
        for (int j = 0; j < 8; ++j) {
            ushort_t h, lo_;
            split_bf16(cw2[(size_t)(k0 + j) * 64 + col], h, lo_);
            out[base + j] = h;
            out[PST + base + j] = lo_;
        }
    }
}

// ===================== x (f32) -> compact bf16 copy ========================
__global__ __launch_bounds__(256) void x2bf(const float* __restrict__ x,
                                            ushort_t* __restrict__ xh, int n4) {
    int g = blockIdx.x * 256 + threadIdx.x;
    if (g >= n4) return;
    float4 v = ((const float4*)x)[g];
    ((uint2*)xh)[g] = pack_bf4(v);
}

// ============= GEMM  Y[M,NCOL] = sum_s A_s[M,128] @ W_s + bias =============
// A_s: bf16 rows 256B. 256 thr / 4 waves (2x2), 64 rows/block.
// FUSE: 0 = bias, f32 out   1 = LN+relu, bf16 out   2 = LN+gelu, bf16 out
//       3 = LN+gelu, f32 out   4 = bias, bf16 out
template <int NCOL, int NSEG, int FUSE>
__global__ __launch_bounds__(256, 3) void gemm_bf(
    const ushort_t* __restrict__ A0, const ushort_t* __restrict__ A1,
    const ushort_t* __restrict__ A2, const ushort_t* __restrict__ A3,
    const ushort_t* __restrict__ wfrag, const float* __restrict__ bias,
    const float* __restrict__ lng, const float* __restrict__ lnb,
    void* __restrict__ Yv, int M) {
    constexpr int NCF = NCOL / 16;
    constexpr int WF = NCOL / 32;
    constexpr int PST = 4 * NCF * 512;
    constexpr int WSEG = 2 * PST;
    constexpr int RS = NCOL * 4 + 16;
    constexpr int EPB = 64 * RS;
    constexpr int SMEM_BYTES = (EPB > 16384) ? EPB : 16384;
    __shared__ __align__(16) char smem[SMEM_BYTES];
    char (*lds)[8192] = (char(*)[8192])smem;

    const int tid = threadIdx.x;
    const int wv = tid >> 6, lane = tid & 63, l15 = lane & 15, lg = lane >> 4;
    const int rowgrp = wv >> 1, colgrp = wv & 1;
    const int row0 = blockIdx.x * 64;
    const ushort_t* As[4] = {A0, A1, A2, A3};

    f32x4 acc[2][WF];
#pragma unroll
    for (int xf = 0; xf < 2; ++xf)
#pragma unroll
        for (int wf = 0; wf < WF; ++wf) acc[xf][wf] = (f32x4){0.f, 0.f, 0.f, 0.f};

    uint4 regs[2];

    auto LOADSTAGE = [&](int ch) {
        const ushort_t* __restrict__ A = As[ch >> 1];
        int kcb = (ch & 1) * 128;            // byte offset of k-chunk in row
#pragma unroll
        for (int i = 0; i < 2; ++i) {
            int s = tid + i * 256;           // 512 slots: 64r x 8 c16
            int r = s >> 3, c16 = s & 7;
            int gr = row0 + r;
            uint4 v = make_uint4(0u, 0u, 0u, 0u);
            if (gr < M)
                v = *(const uint4*)((const char*)A + (size_t)gr * 256 + kcb + c16 * 16);
            regs[i] = v;
        }
    };

    auto WRITESTAGE = [&](int buf) {
        char* L = lds[buf];
#pragma unroll
        for (int i = 0; i < 2; ++i) {
            int s = tid + i * 256;
            int r = s >> 3, c16 = s & 7;
            int byte = (r * 128 + c16 * 16) ^ ((r & 7) << 4);
            *(uint4*)(L + byte) = regs[i];
        }
    };

    auto COMPUTE = [&](int ch, int buf) {
        int seg = ch >> 1, half = ch & 1;
        const ushort_t* __restrict__ ws = wfrag + (size_t)seg * WSEG;
        const char* L = lds[buf];
#pragma unroll
        for (int kk = 0; kk < 2; ++kk) {
            int ks = half * 2 + kk;
            bf16x8 xh[2];
#pragma unroll
            for (int xf = 0; xf < 2; ++xf) {
                int r = rowgrp * 32 + xf * 16 + l15;
                int byte = (r * 128 + kk * 64 + lg * 16) ^ ((r & 7) << 4);
                xh[xf] = *(const bf16x8*)(L + byte);
            }
            bf16x8 wh[WF], wl[WF];
#pragma unroll
            for (int wf = 0; wf < WF; ++wf) {
                size_t off = (((size_t)ks * NCF + colgrp * WF + wf) * 64 + lane) * 8;
                wh[wf] = *(const bf16x8*)(ws + off);
                wl[wf] = *(const bf16x8*)(ws + PST + off);
            }
#pragma unroll
            for (int xf = 0; xf < 2; ++xf)
#pragma unroll
                for (int wf = 0; wf < WF; ++wf) {
                    acc[xf][wf] = __builtin_amdgcn_mfma_f32_16x16x32_bf16(
                        wh[wf], xh[xf], acc[xf][wf], 0, 0, 0);
                    acc[xf][wf] = __builtin_amdgcn_mfma_f32_16x16x32_bf16(
                        wl[wf], xh[xf], acc[xf][wf], 0, 0, 0);
                }
        }
    };

    constexpr int CH = 2 * NSEG;
    LOADSTAGE(0);
    WRITESTAGE(0);
    __syncthreads();
    for (int ch = 0; ch < CH; ++ch) {
        if (ch + 1 < CH) LOADSTAGE(ch + 1);
        COMPUTE(ch, ch & 1);
        __syncthreads();
        if (ch + 1 < CH) WRITESTAGE((ch + 1) & 1);
        __syncthreads();
    }

    // ---- stage acc tile (+bias) into LDS as full f32 rows ----
    {
        float4 bv[WF];
#pragma unroll
        for (int wf = 0; wf < WF; ++wf) {
            int col = colgrp * (NCOL / 2) + wf * 16 + lg * 4;
            bv[wf] = bias ? *(const float4*)(bias + col)
                          : make_float4(0.f, 0.f, 0.f, 0.f);
        }
#pragma unroll
        for (int xf = 0; xf < 2; ++xf) {
            int r = rowgrp * 32 + xf * 16 + l15;
#pragma unroll
            for (int wf = 0; wf < WF; ++wf) {
                int col = colgrp * (NCOL / 2) + wf * 16 + lg * 4;
                float4 o;
                o.x = acc[xf][wf][0] + bv[wf].x;
                o.y = acc[xf][wf][1] + bv[wf].y;
                o.z = acc[xf][wf][2] + bv[wf].z;
                o.w = acc[xf][wf][3] + bv[wf].w;
                *(float4*)(smem + r * RS + col * 4) = o;
            }
        }
    }
    __syncthreads();

    if (FUSE >= 1 && FUSE <= 3) {
        constexpr int CPT = NCOL / 4;
        int r = tid >> 2, seg = tid & 3;
        char* rp = smem + r * RS + seg * CPT * 4;
        float s = 0.f, sq = 0.f;
        float4 vv[CPT / 4];
#pragma unroll
        for (int j = 0; j < CPT / 4; ++j) {
            float4 v = *(const float4*)(rp + j * 16);
            vv[j] = v;
            s += (v.x + v.y) + (v.z + v.w);
            sq += (v.x * v.x + v.y * v.y) + (v.z * v.z + v.w * v.w);
        }
        s += __shfl_xor(s, 1, 64); sq += __shfl_xor(sq, 1, 64);
        s += __shfl_xor(s, 2, 64); sq += __shfl_xor(sq, 2, 64);
        float mu = s * (1.f / NCOL);
        float var = sq * (1.f / NCOL) - mu * mu;
        float rstd = rsqrtf(var + 1e-5f);
#pragma unroll
        for (int j = 0; j < CPT / 4; ++j) {
            int c0 = seg * CPT + j * 4;
            float4 v = vv[j];
            float4 gg = *(const float4*)(lng + c0);
            float4 bb = *(const float4*)(lnb + c0);
            float y0 = (v.x - mu) * rstd * gg.x + bb.x;
            float y1 = (v.y - mu) * rstd * gg.y + bb.y;
            float y2 = (v.z - mu) * rstd * gg.z + bb.z;
            float y3 = (v.w - mu) * rstd * gg.w + bb.w;
            if (FUSE == 1) {
                y0 = fmaxf(y0, 0.f); y1 = fmaxf(y1, 0.f);
                y2 = fmaxf(y2, 0.f); y3 = fmaxf(y3, 0.f);
            } else {
                y0 = 0.5f * y0 * (1.f + erff(y0 * 0.70710678118654752f));
                y1 = 0.5f * y1 * (1.f + erff(y1 * 0.70710678118654752f));
                y2 = 0.5f * y2 * (1.f + erff(y2 * 0.70710678118654752f));
                y3 = 0.5f * y3 * (1.f + erff(y3 * 0.70710678118654752f));
            }
            vv[j] = make_float4(y0, y1, y2, y3);
        }
        __syncthreads();
        if (FUSE == 3) {
#pragma unroll
            for (int j = 0; j < CPT / 4; ++j) *(float4*)(rp + j * 16) = vv[j];
        } else {
            // bf16 row region: first NCOL*2 bytes at base r*RS
#pragma unroll
            for (int j = 0; j < CPT / 4; ++j) {
                int c0 = seg * CPT + j * 4;
                *(uint2*)(smem + r * RS + 2 * c0) = pack_bf4(vv[j]);
            }
        }
        __syncthreads();
    }

    // ---- contiguous copy-out ----
    if (FUSE == 4) {
        constexpr int SL = 64 * (NCOL / 8);    // uint4 slots (bf16 rows)
#pragma unroll
        for (int i = 0; i < SL / 256; ++i) {
            int slot = tid + i * 256;
            int rr = slot / (NCOL / 8), c16 = slot % (NCOL / 8);
            int gr = row0 + rr;
            if (gr < M) {
                float4 a = *(const float4*)(smem + rr * RS + c16 * 32);
                float4 b = *(const float4*)(smem + rr * RS + c16 * 32 + 16);
                uint4 o;
                uint2 pa = pack_bf4(a), pb = pack_bf4(b);
                o.x = pa.x; o.y = pa.y; o.z = pb.x; o.w = pb.y;
                *(uint4*)((char*)Yv + (size_t)gr * (NCOL * 2) + c16 * 16) = o;
            }
        }
    } else {
        constexpr int OUTB = (FUSE == 0 || FUSE == 3) ? NCOL * 4 : NCOL * 2;
        constexpr int RP = OUTB / 16;
        constexpr int SL = 64 * RP;
#pragma unroll
        for (int i = 0; i < SL / 256; ++i) {
            int slot = tid + i * 256;
            int rr = slot / RP, c16 = slot % RP;
            int gr = row0 + rr;
            if (gr < M)
                *(uint4*)((char*)Yv + (size_t)gr * OUTB + c16 * 16) =
                    *(const uint4*)(smem + rr * RS + c16 * 16);
        }
    }
}

// ======== conv2 multi-head GEMM: x1 staged once, 4 SEQUENTIAL sets =========
// set 0 -> acc bf16 (+b2); sets 1-3 -> H_r bf16 rows.
// Single bf16 epilogue tile (17KB); each set's store drain overlaps the
// next set's MFMA (drain happens at the barrier AFTER that MFMA).
__global__ __launch_bounds__(256, 3) void gemm_conv2(
    const ushort_t* __restrict__ X, const ushort_t* __restrict__ wfb,
    const float* __restrict__ b2, ushort_t* __restrict__ ACbf,
    ushort_t* __restrict__ H0, ushort_t* __restrict__ H1,
    ushort_t* __restrict__ H2, int M) {
    constexpr int NCF = 8, WF = 4;
    constexpr int PST = 4 * NCF * 512;
    constexpr int RS2 = 256 + 16;                 // bf16 epilogue row stride
    __shared__ __align__(16) char smem[16384 + 64 * RS2];   // 33792
    char* Xs = smem;
    char* ep = smem + 16384;

    const int tid = threadIdx.x;
    const int wv = tid >> 6, lane = tid & 63, l15 = lane & 15, lg = lane >> 4;
    const int rowgrp = wv >> 1, colgrp = wv & 1;
    const int row0 = blockIdx.x * 64;

    // stage full X tile [64r][128k] bf16, swizzled
#pragma unroll
    for (int i = 0; i < 4; ++i) {
        int s = tid + i * 256;               // 1024 slots
        int r = s >> 4, c16 = s & 15;
        int gr = row0 + r;
        uint4 v = make_uint4(0u, 0u, 0u, 0u);
        if (gr < M) v = *(const uint4*)((const char*)X + (size_t)gr * 256 + c16 * 16);
        int byte = (r * 256 + c16 * 16) ^ ((r & 7) << 4);
        *(uint4*)(Xs + byte) = v;
    }
    __syncthreads();

    ushort_t* outs[4] = {ACbf, H0, H1, H2};
    for (int set = 0; set < 4; ++set) {
        const ushort_t* __restrict__ ws = wfb + (size_t)(4 + set) * 32768;
        f32x4 acc[2][WF];
#pragma unroll
        for (int xf = 0; xf < 2; ++xf)
#pragma unroll
            for (int wf = 0; wf < WF; ++wf) acc[xf][wf] = (f32x4){0.f, 0.f, 0.f, 0.f};
#pragma unroll
        for (int ks = 0; ks < 4; ++ks) {
            bf16x8 xh[2];
#pragma unroll
            for (int xf = 0; xf < 2; ++xf) {
                int r = rowgrp * 32 + xf * 16 + l15;
                int byte = (r * 256 + ks * 64 + lg * 16) ^ ((r & 7) << 4);
                xh[xf] = *(const bf16x8*)(Xs + byte);
            }
            bf16x8 wh[WF], wl[WF];
#pragma unroll
            for (int wf = 0; wf < WF; ++wf) {
                size_t off = (((size_t)ks * NCF + colgrp * WF + wf) * 64 + lane) * 8;
                wh[wf] = *(const bf16x8*)(ws + off);
                wl[wf] = *(const bf16x8*)(ws + PST + off);
            }
#pragma unroll
            for (int xf = 0; xf < 2; ++xf)
#pragma unroll
                for (int wf = 0; wf < WF; ++wf) {
                    acc[xf][wf] = __builtin_amdgcn_mfma_f32_16x16x32_bf16(
                        wh[wf], xh[xf], acc[xf][wf], 0, 0, 0);
                    acc[xf][wf] = __builtin_amdgcn_mfma_f32_16x16x32_bf16(
                        wl[wf], xh[xf], acc[xf][wf], 0, 0, 0);
                }
        }
        __syncthreads();   // prior set's copy-out LDS reads done (+store drain,
                           // overlapped with the MFMA loop above)
        // stage bf16 tile (+bias for set 0)
#pragma unroll
        for (int xf = 0; xf < 2; ++xf) {
            int r = rowgrp * 32 + xf * 16 + l15;
#pragma unroll
            for (int wf = 0; wf < WF; ++wf) {
                int col = colgrp * 64 + wf * 16 + lg * 4;
                float4 o;
                o.x = acc[xf][wf][0];
                o.y = acc[xf][wf][1];
                o.z = acc[xf][wf][2];
                o.w = acc[xf][wf][3];
                if (set == 0) {
                    float4 bv = *(const float4*)(b2 + col);
                    o.x += bv.x; o.y += bv.y; o.z += bv.z; o.w += bv.w;
                }
                *(uint2*)(ep + r * RS2 + col * 2) = pack_bf4(o);
            }
        }
        __syncthreads();
        // contiguous copy-out (full 256B rows)
        ushort_t* O = outs[set];
#pragma unroll
        for (int i = 0; i < 4; ++i) {
            int slot = tid + i * 256;    // 1024: 64r x 16 c16
            int rr = slot >> 4, c16 = slot & 15;
            int gr = row0 + rr;
            if (gr < M)
                *(uint4*)((char*)O + (size_t)gr * 256 + c16 * 16) =
                    *(const uint4*)(ep + rr * RS2 + c16 * 16);
        }
    }
}

// ============================== CSR build ((dst,rel)-sorted) ===============
__global__ __launch_bounds__(256) void hist3_kernel(const int* __restrict__ edst,
                                                    const int* __restrict__ etype,
                                                    int* __restrict__ deg3, int E) {
    int e = blockIdx.x * 256 + threadIdx.x;
    if (e < E) atomicAdd(&deg3[edst[e] * 3 + etype[e]], 1);
}

__global__ __launch_bounds__(256) void degtot_kernel(const int* __restrict__ deg3,
                                                     int* __restrict__ degtot, int N) {
    int n = blockIdx.x * 256 + threadIdx.x;
    if (n < N) degtot[n] = deg3[n * 3] + deg3[n * 3 + 1] + deg3[n * 3 + 2];
}

__global__ __launch_bounds__(256) void scan_block(const int* __restrict__ in,
                                                  int* __restrict__ out,
                                                  int* __restrict__ sums, int n) {
    __shared__ int s[256];
    int g = blockIdx.x * 256 + threadIdx.x;
    int v = (g < n) ? in[g] : 0;
    s[threadIdx.x] = v;
    __syncthreads();
    int acc = v;
    for (int off = 1; off < 256; off <<= 1) {
        int t = (threadIdx.x >= off) ? s[threadIdx.x - off] : 0;
        __syncthreads();
        acc += t;
        s[threadIdx.x] = acc;
        __syncthreads();
    }
    if (g < n) out[g] = acc - v;
    if (threadIdx.x == 255 && sums) sums[blockIdx.x] = acc;
}

__global__ __launch_bounds__(256) void scan_add(int* __restrict__ out,
                                                const int* __restrict__ topex,
                                                int n, int total) {
    int g = blockIdx.x * 256 + threadIdx.x;
    if (g < n) out[g] += topex[blockIdx.x];
    if (g == 0) out[n] = total;
}

__global__ __launch_bounds__(256) void ranges_kernel(
    const int* __restrict__ rowptr, const int* __restrict__ deg3,
    int4* __restrict__ ranges, int* __restrict__ cursor3, int N) {
    int n = blockIdx.x * 256 + threadIdx.x;
    if (n >= N) return;
    int b = rowptr[n];
    int d0 = deg3[n * 3], d1 = deg3[n * 3 + 1];
    int4 r;
    r.x = b; r.y = b + d0; r.z = b + d0 + d1; r.w = rowptr[n + 1];
    ranges[n] = r;
    cursor3[n * 3] = r.x; cursor3[n * 3 + 1] = r.y; cursor3[n * 3 + 2] = r.z;
}

__global__ __launch_bounds__(256) void fill3_kernel(
    const int* __restrict__ esrc, const int* __restrict__ edst,
    const int* __restrict__ etype, int* __restrict__ cursor3,
    int* __restrict__ colidx, int E) {
    int e = blockIdx.x * 256 + threadIdx.x;
    if (e >= E) return;
    int pos = atomicAdd(&cursor3[edst[e] * 3 + etype[e]], 1);
    colidx[pos] = esrc[e];
}

// ========== fused add-gather from bf16 x -> bf16 S rows ====================
__device__ __forceinline__ float4 gather_sum_bf(const ushort_t* __restrict__ XH,
                                                const int* __restrict__ colidx,
                                                int beg, int end, int l) {
    float4 a = make_float4(0.f, 0.f, 0.f, 0.f);
    int e = beg;
    for (; e + 4 <= end; e += 4) {
        int s0 = colidx[e], s1 = colidx[e + 1];
        int s2 = colidx[e + 2], s3 = colidx[e + 3];
        float4 v0 = unpack_bf4(*(const uint2*)(XH + (size_t)s0 * 128 + l * 4));
        float4 v1 = unpack_bf4(*(const uint2*)(XH + (size_t)s1 * 128 + l * 4));
        float4 v2 = unpack_bf4(*(const uint2*)(XH + (size_t)s2 * 128 + l * 4));
        float4 v3 = unpack_bf4(*(const uint2*)(XH + (size_t)s3 * 128 + l * 4));
        a.x += (v0.x + v1.x) + (v2.x + v3.x);
        a.y += (v0.y + v1.y) + (v2.y + v3.y);
        a.z += (v0.z + v1.z) + (v2.z + v3.z);
        a.w += (v0.w + v1.w) + (v2.w + v3.w);
    }
    for (; e < end; ++e) {
        float4 v = unpack_bf4(*(const uint2*)(XH + (size_t)colidx[e] * 128 + l * 4));
        a.x += v.x; a.y += v.y; a.z += v.z; a.w += v.w;
    }
    return a;
}

__global__ __launch_bounds__(256) void agg3_add(
    const ushort_t* __restrict__ xh, const int4* __restrict__ ranges,
    const int* __restrict__ colidx, ushort_t* __restrict__ S0,
    ushort_t* __restrict__ S1, ushort_t* __restrict__ S2, int N) {
    int node = blockIdx.x * 8 + (threadIdx.x >> 5);
    int l = threadIdx.x & 31;
    if (node >= N) return;
    int4 rg = ranges[node];
    float4 a0 = gather_sum_bf(xh, colidx, rg.x, rg.y, l);
    float4 a1 = gather_sum_bf(xh, colidx, rg.y, rg.z, l);
    float4 a2 = gather_sum_bf(xh, colidx, rg.z, rg.w, l);
    *(uint2*)(S0 + (size_t)node * 128 + l * 4) = pack_bf4(a0);
    *(uint2*)(S1 + (size_t)node * 128 + l * 4) = pack_bf4(a1);
    *(uint2*)(S2 + (size_t)node * 128 + l * 4) = pack_bf4(a2);
}

// ======= fused: acc(bf16) + sum_r max-gather(H_r bf16) -> LN -> relu+resid =
__device__ __forceinline__ float4 gather_max_bf(const ushort_t* __restrict__ H,
                                                const int* __restrict__ colidx,
                                                int beg, int end, int l) {
    float4 m = make_float4(-INFINITY, -INFINITY, -INFINITY, -INFINITY);
    int e = beg;
    for (; e + 4 <= end; e += 4) {
        int s0 = colidx[e], s1 = colidx[e + 1];
        int s2 = colidx[e + 2], s3 = colidx[e + 3];
        float4 v0 = unpack_bf4(*(const uint2*)(H + (size_t)s0 * 128 + l * 4));
        float4 v1 = unpack_bf4(*(const uint2*)(H + (size_t)s1 * 128 + l * 4));
        float4 v2 = unpack_bf4(*(const uint2*)(H + (size_t)s2 * 128 + l * 4));
        float4 v3 = unpack_bf4(*(const uint2*)(H + (size_t)s3 * 128 + l * 4));
        m.x = fmaxf(m.x, fmaxf(fmaxf(v0.x, v1.x), fmaxf(v2.x, v3.x)));
        m.y = fmaxf(m.y, fmaxf(fmaxf(v0.y, v1.y), fmaxf(v2.y, v3.y)));
        m.z = fmaxf(m.z, fmaxf(fmaxf(v0.z, v1.z), fmaxf(v2.z, v3.z)));
        m.w = fmaxf(m.w, fmaxf(fmaxf(v0.w, v1.w), fmaxf(v2.w, v3.w)));
    }
    for (; e < end; ++e) {
        float4 v = unpack_bf4(*(const uint2*)(H + (size_t)colidx[e] * 128 + l * 4));
        m.x = fmaxf(m.x, v.x); m.y = fmaxf(m.y, v.y);
        m.z = fmaxf(m.z, v.z); m.w = fmaxf(m.w, v.w);
    }
    m.x = (m.x > -3e38f) ? m.x : 0.f;
    m.y = (m.y > -3e38f) ? m.y : 0.f;
    m.z = (m.z > -3e38f) ? m.z : 0.f;
    m.w = (m.w > -3e38f) ? m.w : 0.f;
    return m;
}

__global__ __launch_bounds__(256) void maxagg_ln(
    const ushort_t* __restrict__ H0, const ushort_t* __restrict__ H1,
    const ushort_t* __restrict__ H2, const int4* __restrict__ ranges,
    const int* __restrict__ colidx, const ushort_t* __restrict__ accbf,
    const ushort_t* __restrict__ resid, const float* __restrict__ g,
    const float* __restrict__ b, ushort_t* __restrict__ outH, int N) {
    int node = blockIdx.x * 8 + (threadIdx.x >> 5);
    int l = threadIdx.x & 31;
    if (node >= N) return;
    int4 rg = ranges[node];
    float4 m0 = gather_max_bf(H0, colidx, rg.x, rg.y, l);
    float4 m1 = gather_max_bf(H1, colidx, rg.y, rg.z, l);
    float4 m2 = gather_max_bf(H2, colidx, rg.z, rg.w, l);
    float4 a = unpack_bf4(*(const uint2*)(accbf + (size_t)node * 128 + l * 4));
    a.x += m0.x + m1.x + m2.x;
    a.y += m0.y + m1.y + m2.y;
    a.z += m0.z + m1.z + m2.z;
    a.w += m0.w + m1.w + m2.w;
    float s = (a.x + a.y) + (a.z + a.w);
    float sq = (a.x * a.x + a.y * a.y) + (a.z * a.z + a.w * a.w);
#pragma unroll
    for (int off = 16; off; off >>= 1) {
        s += __shfl_xor(s, off, 64);
        sq += __shfl_xor(sq, off, 64);
    }
    float mu = s * (1.f / 128.f);
    float var = sq * (1.f / 128.f) - mu * mu;
    float rstd = rsqrtf(var + 1e-5f);
    float4 gg = *(const float4*)(g + l * 4);
    float4 bb = *(const float4*)(b + l * 4);
    float4 rv = unpack_bf4(*(const uint2*)(resid + (size_t)node * 128 + l * 4));
    float4 y;
    y.x = fmaxf((a.x - mu) * rstd * gg.x + bb.x, 0.f) + 0.2f * rv.x;
    y.y = fmaxf((a.y - mu) * rstd * gg.y + bb.y, 0.f) + 0.2f * rv.y;
    y.z = fmaxf((a.z - mu) * rstd * gg.z + bb.z, 0.f) + 0.2f * rv.z;
    y.w = fmaxf((a.w - mu) * rstd * gg.w + bb.w, 0.f) + 0.2f * rv.w;
    *(uint2*)(outH + (size_t)node * 128 + l * 4) = pack_bf4(y);
}

// ====== f32 GEMM  M x 64 @ 64 x 40 + bias + log_softmax -> out =============
__global__ __launch_bounds__(256) void gemm40_lsm(const float* __restrict__ X,
                                                  const float* __restrict__ W,
                                                  const float* __restrict__ bias,
                                                  float* __restrict__ Y, int M) {
    __shared__ float Xs[64][65];
    __shared__ float Ws[64 * 40];
    __shared__ float Ys[64][41];
    __shared__ float mx_[64], ls_[64];
    const int tid = threadIdx.x;
    const int row0 = blockIdx.x * 64;
    for (int i = tid; i < 64 * 40; i += 256) Ws[i] = W[i];
#pragma unroll
    for (int i = 0; i < 4; ++i) {
        int slot = tid + i * 256;
        int r = slot >> 4, c4 = slot & 15;
        float4 v = make_float4(0.f, 0.f, 0.f, 0.f);
        if (row0 + r < M) v = *(const float4*)(X + (size_t)(row0 + r) * 64 + c4 * 4);
        Xs[r][c4 * 4 + 0] = v.x; Xs[r][c4 * 4 + 1] = v.y;
        Xs[r][c4 * 4 + 2] = v.z; Xs[r][c4 * 4 + 3] = v.w;
    }
    __syncthreads();
    const int row = tid >> 2, cg = (tid & 3) * 10;
    float acc[10];
#pragma unroll
    for (int j = 0; j < 10; ++j) acc[j] = 0.f;
#pragma unroll 8
    for (int k = 0; k < 64; ++k) {
        float xv = Xs[row][k];
#pragma unroll
        for (int j = 0; j < 10; ++j) acc[j] = fmaf(xv, Ws[k * 40 + cg + j], acc[j]);
    }
#pragma unroll
    for (int j = 0; j < 10; ++j) Ys[row][cg + j] = acc[j] + bias[cg + j];
    __syncthreads();
    if (tid < 64) {
        float mx = -INFINITY;
#pragma unroll 8
        for (int c = 0; c < 40; ++c) mx = fmaxf(mx, Ys[tid][c]);
        float sum = 0.f;
#pragma unroll 8
        for (int c = 0; c < 40; ++c) sum += __expf(Ys[tid][c] - mx);
        mx_[tid] = mx;
        ls_[tid] = logf(sum);
    }
    __syncthreads();
#pragma unroll
    for (int i = 0; i < 10; ++i) {
        int slot = tid + i * 256;
        int r = slot / 40, c = slot % 40;
        int gr = row0 + r;
        if (gr < M) Y[(size_t)gr * 40 + c] = Ys[r][c] - mx_[r] - ls_[r];
    }
}

// ===========================================================================
extern "C" void kernel_launch(void* const* d_in, const int* in_sizes, int n_in,
                              void* d_out, int out_size, void* d_ws, size_t ws_size,
                              hipStream_t stream) {
    const float* x       = (const float*)d_in[0];
    const int*   eidx    = (const int*)d_in[1];
    const int*   etype   = (const int*)d_in[2];
    const float* w1_rel  = (const float*)d_in[3];
    const float* w1_root = (const float*)d_in[4];
    const float* b1      = (const float*)d_in[5];
    const float* ln1_g   = (const float*)d_in[6];
    const float* ln1_b   = (const float*)d_in[7];
    const float* w2_rel  = (const float*)d_in[8];
    const float* w2_root = (const float*)d_in[9];
    const float* b2      = (const float*)d_in[10];
    const float* ln2_g   = (const float*)d_in[11];
    const float* ln2_b   = (const float*)d_in[12];
    const float* cw1     = (const float*)d_in[13];
    const float* cb1     = (const float*)d_in[14];
    const float* cln1_g  = (const float*)d_in[15];
    const float* cln1_b  = (const float*)d_in[16];
    const float* cw2     = (const float*)d_in[17];
    const float* cb2     = (const float*)d_in[18];
    const float* cln2_g  = (const float*)d_in[19];
    const float* cln2_b  = (const float*)d_in[20];
    const float* cw3     = (const float*)d_in[21];
    const float* cb3     = (const float*)d_in[22];

    const int N = in_sizes[0] / 128;   // 50000
    const int E = in_sizes[1] / 2;     // 600000
    const int* esrc = eidx;
    const int* edst = eidx + E;

    const size_t HB = (size_t)N * 256;      // one bf16 [N,128] buffer, bytes
    char* base = (char*)d_ws;
    ushort_t* S0 = (ushort_t*)(base + 0 * HB);       // -> H0
    ushort_t* S1 = (ushort_t*)(base + 1 * HB);       // -> H1
    ushort_t* S2 = (ushort_t*)(base + 2 * HB);       // -> H2
    ushort_t* X1 = (ushort_t*)(base + 3 * HB);       // x1 bf16
    ushort_t* AC = (ushort_t*)(base + 4 * HB);       // acc2 bf16
    char*     B3 = base + 5 * HB;                    // META

    int* rowptr  = (int*)B3;                      // N+1
    int* degtot  = rowptr + (N + 1);              // N
    int* deg3    = degtot + N;                    // 3N
    int* cursor3 = deg3 + 3 * N;                  // 3N
    int* bsums   = cursor3 + 3 * N;               // 256
    int* btop    = bsums + 256;                   // 256
    int4* ranges = (int4*)(((uintptr_t)(btop + 256) + 15) & ~(uintptr_t)15);
    int* colidx  = (int*)(ranges + N);            // E
    ushort_t* wfb = (ushort_t*)(((uintptr_t)(colidx + E) + 255) & ~(uintptr_t)255);
    auto WSLOT = [&](int i) { return wfb + (size_t)i * 32768; };
    ushort_t* xh = (ushort_t*)(((uintptr_t)(wfb + 10 * 32768) + 255) & ~(uintptr_t)255);
    ushort_t* h2 = xh;                            // xh dead after conv1 gemm
    ushort_t* C1 = S0;                            // classifier temps reuse
    float*    C2 = (float*)S1;                    // [N,64] f32

    const dim3 blk(256);
    const int gGemm = (N + 63) / 64;
    const int gAgg  = (N + 7) / 8;
    const int gEdge = (E + 255) / 256;
    const int gNode = (N + 255) / 256;
    const int nScanB = (N + 255) / 256;
    const int gX2  = (N * 32 + 255) / 256;

    // ---------------- CSR build ----------------
    hipMemsetAsync(deg3, 0, (size_t)3 * N * sizeof(int), stream);
    hist3_kernel<<<gEdge, blk, 0, stream>>>(edst, etype, deg3, E);
    degtot_kernel<<<gNode, blk, 0, stream>>>(deg3, degtot, N);
    scan_block<<<nScanB, blk, 0, stream>>>(degtot, rowptr, bsums, N);
    scan_block<<<1, blk, 0, stream>>>(bsums, btop, nullptr, nScanB);
    scan_add<<<nScanB, blk, 0, stream>>>(rowptr, btop, N, E);
    ranges_kernel<<<gNode, blk, 0, stream>>>(rowptr, deg3, ranges, cursor3, N);
    fill3_kernel<<<gEdge, blk, 0, stream>>>(esrc, edst, etype, cursor3, colidx, E);

    // ---------------- weights + x conversion ----------------
    convert_all<<<76, blk, 0, stream>>>(w1_root, w1_rel, w2_root, w2_rel,
                                        cw1, cw2, wfb);
    x2bf<<<gX2, blk, 0, stream>>>(x, xh, N * 32);

    // ---------------- conv1 (add) ----------------
    agg3_add<<<gAgg, blk, 0, stream>>>(xh, ranges, colidx, S0, S1, S2, N);
    gemm_bf<128, 4, 1><<<gGemm, blk, 0, stream>>>(
        xh, S0, S1, S2, WSLOT(0), b1, ln1_g, ln1_b, X1, N);   // x1 bf16

    // ---------------- conv2 (max) ----------------
    gemm_conv2<<<gGemm, blk, 0, stream>>>(X1, wfb, b2, AC, S0, S1, S2, N);
    maxagg_ln<<<gAgg, blk, 0, stream>>>(S0, S1, S2, ranges, colidx, AC,
                                        X1, ln2_g, ln2_b, h2, N);

    // ---------------- classifier ----------------
    gemm_bf<128, 1, 2><<<gGemm, blk, 0, stream>>>(
        h2, h2, h2, h2, WSLOT(8), cb1, cln1_g, cln1_b, C1, N);   // bf16
    gemm_bf<64, 1, 3><<<gGemm, blk, 0, stream>>>(
        C1, C1, C1, C1, WSLOT(9), cb2, cln2_g, cln2_b, C2, N);   // f32 [N,64]
    gemm40_lsm<<<gGemm, blk, 0, stream>>>(C2, cw3, cb3, (float*)d_out, N);
}

// Round 13
// 256.892 us; speedup vs baseline: 1.1281x; 1.0389x over previous
//
#include <hip/hip_runtime.h>
#include <hip/hip_bf16.h>
#include <math.h>

// ---------------------------------------------------------------------------
// RGCN forward. ALL activations as single-plane bf16 rows (256B/row);
// weights split-bf16 (hi/lo) in MFMA fragment order -> 2 MFMA per frag.
// conv1: x->bf16, fused add-gather (combined-range, 8-deep MLP), one K=512
//        GEMM + LN1 + relu.
// conv2: ONE multi-head GEMM (x1 staged once; 4 sequential weight sets;
//        bf16 epilogue tile), then ONE fused maxagg+LN2+relu+resid pass
//        (combined-range 8-deep gather over contiguous H0|H1|H2).
// classifier: gemm+LN+gelu x2, gemm40+log_softmax fused.
// All global stores are full-line contiguous (LDS-staged epilogues).
// ---------------------------------------------------------------------------

typedef __attribute__((ext_vector_type(8))) short bf16x8;
typedef __attribute__((ext_vector_type(4))) float f32x4;
typedef unsigned short ushort_t;

__device__ __forceinline__ ushort_t bf16rne(float v) {
    unsigned u = __float_as_uint(v);
    return (ushort_t)((u + 0x7FFFu + ((u >> 16) & 1u)) >> 16);
}

__device__ __forceinline__ void split_bf16(float v, ushort_t& h, ushort_t& l) {
    ushort_t hu = bf16rne(v);
    float hf = __uint_as_float((unsigned)hu << 16);
    h = hu;
    l = bf16rne(v - hf);
}

__device__ __forceinline__ float bf2f(unsigned u16) {
    return __uint_as_float(u16 << 16);
}

__device__ __forceinline__ float4 unpack_bf4(uint2 u) {
    return make_float4(bf2f(u.x & 0xFFFFu), bf2f(u.x >> 16),
                       bf2f(u.y & 0xFFFFu), bf2f(u.y >> 16));
}

__device__ __forceinline__ uint2 pack_bf4(float4 v) {
    uint2 o;
    o.x = (unsigned)bf16rne(v.x) | ((unsigned)bf16rne(v.y) << 16);
    o.y = (unsigned)bf16rne(v.z) | ((unsigned)bf16rne(v.w) << 16);
    return o;
}

// ====== convert ALL weights to fragment order + x->bf16 (ONE launch) =======
// frag layout (ushort): [plane][ks 0..3][cf][lane 0..63][8], slot=32768 ush.
__device__ __forceinline__ void conv_body128(const float* __restrict__ W,
                                             ushort_t* __restrict__ out,
                                             int idx) {
    constexpr int NCF = 8;
    constexpr size_t PST = (size_t)4 * NCF * 512;
    int l = idx & 63;
    int cf = (idx >> 6) & 7;
    int ks = idx >> 9;
    int col = cf * 16 + (l & 15);
    int k0 = ks * 32 + (l >> 4) * 8;
    size_t base = (((size_t)ks * NCF + cf) * 64 + l) * 8;
#pragma unroll
    for (int j = 0; j < 8; ++j) {
        ushort_t h, lo_;
        split_bf16(W[(size_t)(k0 + j) * 128 + col], h, lo_);
        out[base + j] = h;
        out[PST + base + j] = lo_;
    }
}

__global__ __launch_bounds__(256) void convert_all_x2bf(
    const float* __restrict__ w1_root, const float* __restrict__ w1_rel,
    const float* __restrict__ w2_root, const float* __restrict__ w2_rel,
    const float* __restrict__ cw1, const float* __restrict__ cw2,
    ushort_t* __restrict__ wfb,
    const float* __restrict__ x, ushort_t* __restrict__ xh, int n4) {
    int b = blockIdx.x;
    if (b >= 76) {
        int g = (b - 76) * 256 + threadIdx.x;
        if (g < n4) {
            float4 v = ((const float4*)x)[g];
            ((uint2*)xh)[g] = pack_bf4(v);
        }
        return;
    }
    if (b < 72) {
        const float* src;
        int slot;
        if (b < 8)       { slot = 0;              src = w1_root; }
        else if (b < 32) { int r = (b - 8) >> 3;  slot = 1 + r; src = w1_rel + (size_t)r * 16384; }
        else if (b < 40) { slot = 4;              src = w2_root; }
        else if (b < 64) { int r = (b - 40) >> 3; slot = 5 + r; src = w2_rel + (size_t)r * 16384; }
        else             { slot = 8;              src = cw1; }
        int lb = (b < 8) ? b : (b < 32) ? ((b - 8) & 7) : (b < 40) ? (b - 32)
               : (b < 64) ? ((b - 40) & 7) : (b - 64);
        conv_body128(src, wfb + (size_t)slot * 32768, lb * 256 + threadIdx.x);
    } else {
        // slot 9: cw2 K=128 x NCOL=64 -> blocks 72..75, 1024 items exactly
        constexpr int NCF = 4;
        constexpr size_t PST = (size_t)4 * NCF * 512;
        int idx = (b - 72) * 256 + threadIdx.x;   // [0, 1024)
        ushort_t* out = wfb + (size_t)9 * 32768;
        int l = idx & 63;
        int cf = (idx >> 6) & 3;
        int ks = idx >> 8;                        // [0, 4)
        int col = cf * 16 + (l & 15);
        int k0 = ks * 32 + (l >> 4) * 8;
        size_t base = (((size_t)ks * NCF + cf) * 64 + l) * 8;
#pragma unroll
        for (int j = 0; j < 8; ++j) {
            ushort_t h, lo_;
            split_bf16(cw2[(size_t)(k0 + j) * 64 + col], h, lo_);
            out[base + j] = h;
            out[PST + base + j] = lo_;
        }
    }
}

// ============= GEMM  Y[M,NCOL] = sum_s A_s[M,128] @ W_s + bias =============
// A_s: bf16 rows 256B. 256 thr / 4 waves (2x2), 64 rows/block.
// FUSE: 0 = bias, f32 out   1 = LN+relu, bf16 out   2 = LN+gelu, bf16 out
//       3 = LN+gelu, f32 out   4 = bias, bf16 out
template <int NCOL, int NSEG, int FUSE>
__global__ __launch_bounds__(256, 3) void gemm_bf(
    const ushort_t* __restrict__ A0, const ushort_t* __restrict__ A1,
    const ushort_t* __restrict__ A2, const ushort_t* __restrict__ A3,
    const ushort_t* __restrict__ wfrag, const float* __restrict__ bias,
    const float* __restrict__ lng, const float* __restrict__ lnb,
    void* __restrict__ Yv, int M) {
    constexpr int NCF = NCOL / 16;
    constexpr int WF = NCOL / 32;
    constexpr int PST = 4 * NCF * 512;
    constexpr int WSEG = 2 * PST;
    constexpr int RS = NCOL * 4 + 16;
    constexpr int EPB = 64 * RS;
    constexpr int SMEM_BYTES = (EPB > 16384) ? EPB : 16384;
    __shared__ __align__(16) char smem[SMEM_BYTES];
    char (*lds)[8192] = (char(*)[8192])smem;

    const int tid = threadIdx.x;
    const int wv = tid >> 6, lane = tid & 63, l15 = lane & 15, lg = lane >> 4;
    const int rowgrp = wv >> 1, colgrp = wv & 1;
    const int row0 = blockIdx.x * 64;
    const ushort_t* As[4] = {A0, A1, A2, A3};

    f32x4 acc[2][WF];
#pragma unroll
    for (int xf = 0; xf < 2; ++xf)
#pragma unroll
        for (int wf = 0; wf < WF; ++wf) acc[xf][wf] = (f32x4){0.f, 0.f, 0.f, 0.f};

    uint4 regs[2];

    auto LOADSTAGE = [&](int ch) {
        const ushort_t* __restrict__ A = As[ch >> 1];
        int kcb = (ch & 1) * 128;
#pragma unroll
        for (int i = 0; i < 2; ++i) {
            int s = tid + i * 256;
            int r = s >> 3, c16 = s & 7;
            int gr = row0 + r;
            uint4 v = make_uint4(0u, 0u, 0u, 0u);
            if (gr < M)
                v = *(const uint4*)((const char*)A + (size_t)gr * 256 + kcb + c16 * 16);
            regs[i] = v;
        }
    };

    auto WRITESTAGE = [&](int buf) {
        char* L = lds[buf];
#pragma unroll
        for (int i = 0; i < 2; ++i) {
            int s = tid + i * 256;
            int r = s >> 3, c16 = s & 7;
            int byte = (r * 128 + c16 * 16) ^ ((r & 7) << 4);
            *(uint4*)(L + byte) = regs[i];
        }
    };

    auto COMPUTE = [&](int ch, int buf) {
        int seg = ch >> 1, half = ch & 1;
        const ushort_t* __restrict__ ws = wfrag + (size_t)seg * WSEG;
        const char* L = lds[buf];
#pragma unroll
        for (int kk = 0; kk < 2; ++kk) {
            int ks = half * 2 + kk;
            bf16x8 xh[2];
#pragma unroll
            for (int xf = 0; xf < 2; ++xf) {
                int r = rowgrp * 32 + xf * 16 + l15;
                int byte = (r * 128 + kk * 64 + lg * 16) ^ ((r & 7) << 4);
                xh[xf] = *(const bf16x8*)(L + byte);
            }
            bf16x8 wh[WF], wl[WF];
#pragma unroll
            for (int wf = 0; wf < WF; ++wf) {
                size_t off = (((size_t)ks * NCF + colgrp * WF + wf) * 64 + lane) * 8;
                wh[wf] = *(const bf16x8*)(ws + off);
                wl[wf] = *(const bf16x8*)(ws + PST + off);
            }
#pragma unroll
            for (int xf = 0; xf < 2; ++xf)
#pragma unroll
                for (int wf = 0; wf < WF; ++wf) {
                    acc[xf][wf] = __builtin_amdgcn_mfma_f32_16x16x32_bf16(
                        wh[wf], xh[xf], acc[xf][wf], 0, 0, 0);
                    acc[xf][wf] = __builtin_amdgcn_mfma_f32_16x16x32_bf16(
                        wl[wf], xh[xf], acc[xf][wf], 0, 0, 0);
                }
        }
    };

    constexpr int CH = 2 * NSEG;
    LOADSTAGE(0);
    WRITESTAGE(0);
    __syncthreads();
    for (int ch = 0; ch < CH; ++ch) {
        if (ch + 1 < CH) LOADSTAGE(ch + 1);
        COMPUTE(ch, ch & 1);
        __syncthreads();
        if (ch + 1 < CH) WRITESTAGE((ch + 1) & 1);
        __syncthreads();
    }

    // ---- stage acc tile (+bias) into LDS as full f32 rows ----
    {
        float4 bv[WF];
#pragma unroll
        for (int wf = 0; wf < WF; ++wf) {
            int col = colgrp * (NCOL / 2) + wf * 16 + lg * 4;
            bv[wf] = bias ? *(const float4*)(bias + col)
                          : make_float4(0.f, 0.f, 0.f, 0.f);
        }
#pragma unroll
        for (int xf = 0; xf < 2; ++xf) {
            int r = rowgrp * 32 + xf * 16 + l15;
#pragma unroll
            for (int wf = 0; wf < WF; ++wf) {
                int col = colgrp * (NCOL / 2) + wf * 16 + lg * 4;
                float4 o;
                o.x = acc[xf][wf][0] + bv[wf].x;
                o.y = acc[xf][wf][1] + bv[wf].y;
                o.z = acc[xf][wf][2] + bv[wf].z;
                o.w = acc[xf][wf][3] + bv[wf].w;
                *(float4*)(smem + r * RS + col * 4) = o;
            }
        }
    }
    __syncthreads();

    if (FUSE >= 1 && FUSE <= 3) {
        constexpr int CPT = NCOL / 4;
        int r = tid >> 2, seg = tid & 3;
        char* rp = smem + r * RS + seg * CPT * 4;
        float s = 0.f, sq = 0.f;
        float4 vv[CPT / 4];
#pragma unroll
        for (int j = 0; j < CPT / 4; ++j) {
            float4 v = *(const float4*)(rp + j * 16);
            vv[j] = v;
            s += (v.x + v.y) + (v.z + v.w);
            sq += (v.x * v.x + v.y * v.y) + (v.z * v.z + v.w * v.w);
        }
        s += __shfl_xor(s, 1, 64); sq += __shfl_xor(sq, 1, 64);
        s += __shfl_xor(s, 2, 64); sq += __shfl_xor(sq, 2, 64);
        float mu = s * (1.f / NCOL);
        float var = sq * (1.f / NCOL) - mu * mu;
        float rstd = rsqrtf(var + 1e-5f);
#pragma unroll
        for (int j = 0; j < CPT / 4; ++j) {
            int c0 = seg * CPT + j * 4;
            float4 v = vv[j];
            float4 gg = *(const float4*)(lng + c0);
            float4 bb = *(const float4*)(lnb + c0);
            float y0 = (v.x - mu) * rstd * gg.x + bb.x;
            float y1 = (v.y - mu) * rstd * gg.y + bb.y;
            float y2 = (v.z - mu) * rstd * gg.z + bb.z;
            float y3 = (v.w - mu) * rstd * gg.w + bb.w;
            if (FUSE == 1) {
                y0 = fmaxf(y0, 0.f); y1 = fmaxf(y1, 0.f);
                y2 = fmaxf(y2, 0.f); y3 = fmaxf(y3, 0.f);
            } else {
                y0 = 0.5f * y0 * (1.f + erff(y0 * 0.70710678118654752f));
                y1 = 0.5f * y1 * (1.f + erff(y1 * 0.70710678118654752f));
                y2 = 0.5f * y2 * (1.f + erff(y2 * 0.70710678118654752f));
                y3 = 0.5f * y3 * (1.f + erff(y3 * 0.70710678118654752f));
            }
            vv[j] = make_float4(y0, y1, y2, y3);
        }
        __syncthreads();
        if (FUSE == 3) {
#pragma unroll
            for (int j = 0; j < CPT / 4; ++j) *(float4*)(rp + j * 16) = vv[j];
        } else {
#pragma unroll
            for (int j = 0; j < CPT / 4; ++j) {
                int c0 = seg * CPT + j * 4;
                *(uint2*)(smem + r * RS + 2 * c0) = pack_bf4(vv[j]);
            }
        }
        __syncthreads();
    }

    // ---- contiguous copy-out ----
    if (FUSE == 4) {
        constexpr int SL = 64 * (NCOL / 8);
#pragma unroll
        for (int i = 0; i < SL / 256; ++i) {
            int slot = tid + i * 256;
            int rr = slot / (NCOL / 8), c16 = slot % (NCOL / 8);
            int gr = row0 + rr;
            if (gr < M) {
                float4 a = *(const float4*)(smem + rr * RS + c16 * 32);
                float4 b = *(const float4*)(smem + rr * RS + c16 * 32 + 16);
                uint4 o;
                uint2 pa = pack_bf4(a), pb = pack_bf4(b);
                o.x = pa.x; o.y = pa.y; o.z = pb.x; o.w = pb.y;
                *(uint4*)((char*)Yv + (size_t)gr * (NCOL * 2) + c16 * 16) = o;
            }
        }
    } else {
        constexpr int OUTB = (FUSE == 0 || FUSE == 3) ? NCOL * 4 : NCOL * 2;
        constexpr int RP = OUTB / 16;
        constexpr int SL = 64 * RP;
#pragma unroll
        for (int i = 0; i < SL / 256; ++i) {
            int slot = tid + i * 256;
            int rr = slot / RP, c16 = slot % RP;
            int gr = row0 + rr;
            if (gr < M)
                *(uint4*)((char*)Yv + (size_t)gr * OUTB + c16 * 16) =
                    *(const uint4*)(smem + rr * RS + c16 * 16);
        }
    }
}

// ======== conv2 multi-head GEMM: x1 staged once, 4 SEQUENTIAL sets =========
__global__ __launch_bounds__(256, 3) void gemm_conv2(
    const ushort_t* __restrict__ X, const ushort_t* __restrict__ wfb,
    const float* __restrict__ b2, ushort_t* __restrict__ ACbf,
    ushort_t* __restrict__ H0, ushort_t* __restrict__ H1,
    ushort_t* __restrict__ H2, int M) {
    constexpr int NCF = 8, WF = 4;
    constexpr int PST = 4 * NCF * 512;
    constexpr int RS2 = 256 + 16;
    __shared__ __align__(16) char smem[16384 + 64 * RS2];   // 33792
    char* Xs = smem;
    char* ep = smem + 16384;

    const int tid = threadIdx.x;
    const int wv = tid >> 6, lane = tid & 63, l15 = lane & 15, lg = lane >> 4;
    const int rowgrp = wv >> 1, colgrp = wv & 1;
    const int row0 = blockIdx.x * 64;

#pragma unroll
    for (int i = 0; i < 4; ++i) {
        int s = tid + i * 256;
        int r = s >> 4, c16 = s & 15;
        int gr = row0 + r;
        uint4 v = make_uint4(0u, 0u, 0u, 0u);
        if (gr < M) v = *(const uint4*)((const char*)X + (size_t)gr * 256 + c16 * 16);
        int byte = (r * 256 + c16 * 16) ^ ((r & 7) << 4);
        *(uint4*)(Xs + byte) = v;
    }
    __syncthreads();

    ushort_t* outs[4] = {ACbf, H0, H1, H2};
    for (int set = 0; set < 4; ++set) {
        const ushort_t* __restrict__ ws = wfb + (size_t)(4 + set) * 32768;
        f32x4 acc[2][WF];
#pragma unroll
        for (int xf = 0; xf < 2; ++xf)
#pragma unroll
            for (int wf = 0; wf < WF; ++wf) acc[xf][wf] = (f32x4){0.f, 0.f, 0.f, 0.f};
#pragma unroll
        for (int ks = 0; ks < 4; ++ks) {
            bf16x8 xh[2];
#pragma unroll
            for (int xf = 0; xf < 2; ++xf) {
                int r = rowgrp * 32 + xf * 16 + l15;
                int byte = (r * 256 + ks * 64 + lg * 16) ^ ((r & 7) << 4);
                xh[xf] = *(const bf16x8*)(Xs + byte);
            }
            bf16x8 wh[WF], wl[WF];
#pragma unroll
            for (int wf = 0; wf < WF; ++wf) {
                size_t off = (((size_t)ks * NCF + colgrp * WF + wf) * 64 + lane) * 8;
                wh[wf] = *(const bf16x8*)(ws + off);
                wl[wf] = *(const bf16x8*)(ws + PST + off);
            }
#pragma unroll
            for (int xf = 0; xf < 2; ++xf)
#pragma unroll
                for (int wf = 0; wf < WF; ++wf) {
                    acc[xf][wf] = __builtin_amdgcn_mfma_f32_16x16x32_bf16(
                        wh[wf], xh[xf], acc[xf][wf], 0, 0, 0);
                    acc[xf][wf] = __builtin_amdgcn_mfma_f32_16x16x32_bf16(
                        wl[wf], xh[xf], acc[xf][wf], 0, 0, 0);
                }
        }
        __syncthreads();
#pragma unroll
        for (int xf = 0; xf < 2; ++xf) {
            int r = rowgrp * 32 + xf * 16 + l15;
#pragma unroll
            for (int wf = 0; wf < WF; ++wf) {
                int col = colgrp * 64 + wf * 16 + lg * 4;
                float4 o;
                o.x = acc[xf][wf][0];
                o.y = acc[xf][wf][1];
                o.z = acc[xf][wf][2];
                o.w = acc[xf][wf][3];
                if (set == 0) {
                    float4 bv = *(const float4*)(b2 + col);
                    o.x += bv.x; o.y += bv.y; o.z += bv.z; o.w += bv.w;
                }
                *(uint2*)(ep + r * RS2 + col * 2) = pack_bf4(o);
            }
        }
        __syncthreads();
        ushort_t* O = outs[set];
#pragma unroll
        for (int i = 0; i < 4; ++i) {
            int slot = tid + i * 256;
            int rr = slot >> 4, c16 = slot & 15;
            int gr = row0 + rr;
            if (gr < M)
                *(uint4*)((char*)O + (size_t)gr * 256 + c16 * 16) =
                    *(const uint4*)(ep + rr * RS2 + c16 * 16);
        }
    }
}

// ============================== CSR build ((dst,rel)-sorted) ===============
__global__ __launch_bounds__(256) void hist3_kernel(const int* __restrict__ edst,
                                                    const int* __restrict__ etype,
                                                    int* __restrict__ deg3, int E) {
    int e = blockIdx.x * 256 + threadIdx.x;
    if (e < E) atomicAdd(&deg3[edst[e] * 3 + etype[e]], 1);
}

// per-node total degree scan (reads deg3 directly), block-local exclusive
__global__ __launch_bounds__(256) void scan_deg3(const int* __restrict__ deg3,
                                                 int* __restrict__ out,
                                                 int* __restrict__ sums, int n) {
    __shared__ int s[256];
    int g = blockIdx.x * 256 + threadIdx.x;
    int v = 0;
    if (g < n) v = deg3[g * 3] + deg3[g * 3 + 1] + deg3[g * 3 + 2];
    s[threadIdx.x] = v;
    __syncthreads();
    int acc = v;
    for (int off = 1; off < 256; off <<= 1) {
        int t = (threadIdx.x >= off) ? s[threadIdx.x - off] : 0;
        __syncthreads();
        acc += t;
        s[threadIdx.x] = acc;
        __syncthreads();
    }
    if (g < n) out[g] = acc - v;
    if (threadIdx.x == 255 && sums) sums[blockIdx.x] = acc;
}

__global__ __launch_bounds__(256) void scan_block(const int* __restrict__ in,
                                                  int* __restrict__ out,
                                                  int* __restrict__ sums, int n) {
    __shared__ int s[256];
    int g = blockIdx.x * 256 + threadIdx.x;
    int v = (g < n) ? in[g] : 0;
    s[threadIdx.x] = v;
    __syncthreads();
    int acc = v;
    for (int off = 1; off < 256; off <<= 1) {
        int t = (threadIdx.x >= off) ? s[threadIdx.x - off] : 0;
        __syncthreads();
        acc += t;
        s[threadIdx.x] = acc;
        __syncthreads();
    }
    if (g < n) out[g] = acc - v;
    if (threadIdx.x == 255 && sums) sums[blockIdx.x] = acc;
}

// finalize scan + emit ranges + cursors in one pass
__global__ __launch_bounds__(256) void scan_add_ranges(
    const int* __restrict__ scanned, const int* __restrict__ topex,
    const int* __restrict__ deg3, int4* __restrict__ ranges,
    int* __restrict__ cursor3, int n) {
    int g = blockIdx.x * 256 + threadIdx.x;
    if (g >= n) return;
    int b = scanned[g] + topex[blockIdx.x];
    int d0 = deg3[g * 3], d1 = deg3[g * 3 + 1], d2 = deg3[g * 3 + 2];
    int4 r;
    r.x = b; r.y = b + d0; r.z = b + d0 + d1; r.w = b + d0 + d1 + d2;
    ranges[g] = r;
    cursor3[g * 3] = r.x; cursor3[g * 3 + 1] = r.y; cursor3[g * 3 + 2] = r.z;
}

__global__ __launch_bounds__(256) void fill3_kernel(
    const int* __restrict__ esrc, const int* __restrict__ edst,
    const int* __restrict__ etype, int* __restrict__ cursor3,
    int* __restrict__ colidx, int E) {
    int e = blockIdx.x * 256 + threadIdx.x;
    if (e >= E) return;
    int pos = atomicAdd(&cursor3[edst[e] * 3 + etype[e]], 1);
    colidx[pos] = esrc[e];
}

// ===== conv1 add-gather: COMBINED range, 8-deep, select-accumulate =========
__global__ __launch_bounds__(256) void agg3_add(
    const ushort_t* __restrict__ xh, const int4* __restrict__ ranges,
    const int* __restrict__ colidx, ushort_t* __restrict__ S0,
    ushort_t* __restrict__ S1, ushort_t* __restrict__ S2, int N) {
    int node = blockIdx.x * 8 + (threadIdx.x >> 5);
    int l = threadIdx.x & 31;
    if (node >= N) return;
    int4 rg = ranges[node];
    float4 a0 = make_float4(0.f, 0.f, 0.f, 0.f);
    float4 a1 = a0, a2 = a0;
    int e = rg.x, end = rg.w;

    auto acc1 = [&](int ee, uint2 u) {
        float4 v = unpack_bf4(u);
        bool i0 = ee < rg.y;
        bool i2 = ee >= rg.z;
        bool i1 = !i0 && !i2;
        a0.x += i0 ? v.x : 0.f; a0.y += i0 ? v.y : 0.f;
        a0.z += i0 ? v.z : 0.f; a0.w += i0 ? v.w : 0.f;
        a1.x += i1 ? v.x : 0.f; a1.y += i1 ? v.y : 0.f;
        a1.z += i1 ? v.z : 0.f; a1.w += i1 ? v.w : 0.f;
        a2.x += i2 ? v.x : 0.f; a2.y += i2 ? v.y : 0.f;
        a2.z += i2 ? v.z : 0.f; a2.w += i2 ? v.w : 0.f;
    };

    for (; e + 8 <= end; e += 8) {
        int s[8];
#pragma unroll
        for (int k = 0; k < 8; ++k) s[k] = colidx[e + k];
        uint2 u[8];
#pragma unroll
        for (int k = 0; k < 8; ++k)
            u[k] = *(const uint2*)(xh + (size_t)s[k] * 128 + l * 4);
#pragma unroll
        for (int k = 0; k < 8; ++k) acc1(e + k, u[k]);
    }
    if (e + 4 <= end) {
        int s[4];
#pragma unroll
        for (int k = 0; k < 4; ++k) s[k] = colidx[e + k];
        uint2 u[4];
#pragma unroll
        for (int k = 0; k < 4; ++k)
            u[k] = *(const uint2*)(xh + (size_t)s[k] * 128 + l * 4);
#pragma unroll
        for (int k = 0; k < 4; ++k) acc1(e + k, u[k]);
        e += 4;
    }
    for (; e < end; ++e)
        acc1(e, *(const uint2*)(xh + (size_t)colidx[e] * 128 + l * 4));

    *(uint2*)(S0 + (size_t)node * 128 + l * 4) = pack_bf4(a0);
    *(uint2*)(S1 + (size_t)node * 128 + l * 4) = pack_bf4(a1);
    *(uint2*)(S2 + (size_t)node * 128 + l * 4) = pack_bf4(a2);
}

// == conv2: acc(bf16) + max-gather over contiguous H (rel-offset) + LN + res =
__global__ __launch_bounds__(256) void maxagg_ln(
    const ushort_t* __restrict__ Hbase, const int4* __restrict__ ranges,
    const int* __restrict__ colidx, const ushort_t* __restrict__ accbf,
    const ushort_t* __restrict__ resid, const float* __restrict__ g,
    const float* __restrict__ b, ushort_t* __restrict__ outH, int N) {
    int node = blockIdx.x * 8 + (threadIdx.x >> 5);
    int l = threadIdx.x & 31;
    if (node >= N) return;
    int4 rg = ranges[node];
    const float NI = -INFINITY;
    float4 m0 = make_float4(NI, NI, NI, NI);
    float4 m1 = m0, m2 = m0;
    int e = rg.x, end = rg.w;

    auto acc1 = [&](int ee, uint2 u) {
        float4 v = unpack_bf4(u);
        bool i0 = ee < rg.y;
        bool i2 = ee >= rg.z;
        bool i1 = !i0 && !i2;
        m0.x = fmaxf(m0.x, i0 ? v.x : NI); m0.y = fmaxf(m0.y, i0 ? v.y : NI);
        m0.z = fmaxf(m0.z, i0 ? v.z : NI); m0.w = fmaxf(m0.w, i0 ? v.w : NI);
        m1.x = fmaxf(m1.x, i1 ? v.x : NI); m1.y = fmaxf(m1.y, i1 ? v.y : NI);
        m1.z = fmaxf(m1.z, i1 ? v.z : NI); m1.w = fmaxf(m1.w, i1 ? v.w : NI);
        m2.x = fmaxf(m2.x, i2 ? v.x : NI); m2.y = fmaxf(m2.y, i2 ? v.y : NI);
        m2.z = fmaxf(m2.z, i2 ? v.z : NI); m2.w = fmaxf(m2.w, i2 ? v.w : NI);
    };
    auto addr = [&](int ee, int src) {
        int rel = (ee >= rg.y) + (ee >= rg.z);
        return Hbase + ((size_t)rel * N + src) * 128 + l * 4;
    };

    for (; e + 8 <= end; e += 8) {
        int s[8];
#pragma unroll
        for (int k = 0; k < 8; ++k) s[k] = colidx[e + k];
        uint2 u[8];
#pragma unroll
        for (int k = 0; k < 8; ++k) u[k] = *(const uint2*)addr(e + k, s[k]);
#pragma unroll
        for (int k = 0; k < 8; ++k) acc1(e + k, u[k]);
    }
    if (e + 4 <= end) {
        int s[4];
#pragma unroll
        for (int k = 0; k < 4; ++k) s[k] = colidx[e + k];
        uint2 u[4];
#pragma unroll
        for (int k = 0; k < 4; ++k) u[k] = *(const uint2*)(addr(e + k, s[k]));
#pragma unroll
        for (int k = 0; k < 4; ++k) acc1(e + k, u[k]);
        e += 4;
    }
    for (; e < end; ++e) acc1(e, *(const uint2*)addr(e, colidx[e]));

    auto fix = [](float4& m) {
        m.x = (m.x > -3e38f) ? m.x : 0.f;
        m.y = (m.y > -3e38f) ? m.y : 0.f;
        m.z = (m.z > -3e38f) ? m.z : 0.f;
        m.w = (m.w > -3e38f) ? m.w : 0.f;
    };
    fix(m0); fix(m1); fix(m2);

    float4 a = unpack_bf4(*(const uint2*)(accbf + (size_t)node * 128 + l * 4));
    a.x += m0.x + m1.x + m2.x;
    a.y += m0.y + m1.y + m2.y;
    a.z += m0.z + m1.z + m2.z;
    a.w += m0.w + m1.w + m2.w;
    float s = (a.x + a.y) + (a.z + a.w);
    float sq = (a.x * a.x + a.y * a.y) + (a.z * a.z + a.w * a.w);
#pragma unroll
    for (int off = 16; off; off >>= 1) {
        s += __shfl_xor(s, off, 64);
        sq += __shfl_xor(sq, off, 64);
    }
    float mu = s * (1.f / 128.f);
    float var = sq * (1.f / 128.f) - mu * mu;
    float rstd = rsqrtf(var + 1e-5f);
    float4 gg = *(const float4*)(g + l * 4);
    float4 bb = *(const float4*)(b + l * 4);
    float4 rv = unpack_bf4(*(const uint2*)(resid + (size_t)node * 128 + l * 4));
    float4 y;
    y.x = fmaxf((a.x - mu) * rstd * gg.x + bb.x, 0.f) + 0.2f * rv.x;
    y.y = fmaxf((a.y - mu) * rstd * gg.y + bb.y, 0.f) + 0.2f * rv.y;
    y.z = fmaxf((a.z - mu) * rstd * gg.z + bb.z, 0.f) + 0.2f * rv.z;
    y.w = fmaxf((a.w - mu) * rstd * gg.w + bb.w, 0.f) + 0.2f * rv.w;
    *(uint2*)(outH + (size_t)node * 128 + l * 4) = pack_bf4(y);
}

// ====== f32 GEMM  M x 64 @ 64 x 40 + bias + log_softmax -> out =============
__global__ __launch_bounds__(256) void gemm40_lsm(const float* __restrict__ X,
                                                  const float* __restrict__ W,
                                                  const float* __restrict__ bias,
                                                  float* __restrict__ Y, int M) {
    __shared__ float Xs[64][65];
    __shared__ float Ws[64 * 40];
    __shared__ float Ys[64][41];
    __shared__ float mx_[64], ls_[64];
    const int tid = threadIdx.x;
    const int row0 = blockIdx.x * 64;
    for (int i = tid; i < 64 * 40; i += 256) Ws[i] = W[i];
#pragma unroll
    for (int i = 0; i < 4; ++i) {
        int slot = tid + i * 256;
        int r = slot >> 4, c4 = slot & 15;
        float4 v = make_float4(0.f, 0.f, 0.f, 0.f);
        if (row0 + r < M) v = *(const float4*)(X + (size_t)(row0 + r) * 64 + c4 * 4);
        Xs[r][c4 * 4 + 0] = v.x; Xs[r][c4 * 4 + 1] = v.y;
        Xs[r][c4 * 4 + 2] = v.z; Xs[r][c4 * 4 + 3] = v.w;
    }
    __syncthreads();
    const int row = tid >> 2, cg = (tid & 3) * 10;
    float acc[10];
#pragma unroll
    for (int j = 0; j < 10; ++j) acc[j] = 0.f;
#pragma unroll 8
    for (int k = 0; k < 64; ++k) {
        float xv = Xs[row][k];
#pragma unroll
        for (int j = 0; j < 10; ++j) acc[j] = fmaf(xv, Ws[k * 40 + cg + j], acc[j]);
    }
#pragma unroll
    for (int j = 0; j < 10; ++j) Ys[row][cg + j] = acc[j] + bias[cg + j];
    __syncthreads();
    if (tid < 64) {
        float mx = -INFINITY;
#pragma unroll 8
        for (int c = 0; c < 40; ++c) mx = fmaxf(mx, Ys[tid][c]);
        float sum = 0.f;
#pragma unroll 8
        for (int c = 0; c < 40; ++c) sum += __expf(Ys[tid][c] - mx);
        mx_[tid] = mx;
        ls_[tid] = logf(sum);
    }
    __syncthreads();
#pragma unroll
    for (int i = 0; i < 10; ++i) {
        int slot = tid + i * 256;
        int r = slot / 40, c = slot % 40;
        int gr = row0 + r;
        if (gr < M) Y[(size_t)gr * 40 + c] = Ys[r][c] - mx_[r] - ls_[r];
    }
}

// ===========================================================================
extern "C" void kernel_launch(void* const* d_in, const int* in_sizes, int n_in,
                              void* d_out, int out_size, void* d_ws, size_t ws_size,
                              hipStream_t stream) {
    const float* x       = (const float*)d_in[0];
    const int*   eidx    = (const int*)d_in[1];
    const int*   etype   = (const int*)d_in[2];
    const float* w1_rel  = (const float*)d_in[3];
    const float* w1_root = (const float*)d_in[4];
    const float* b1      = (const float*)d_in[5];
    const float* ln1_g   = (const float*)d_in[6];
    const float* ln1_b   = (const float*)d_in[7];
    const float* w2_rel  = (const float*)d_in[8];
    const float* w2_root = (const float*)d_in[9];
    const float* b2      = (const float*)d_in[10];
    const float* ln2_g   = (const float*)d_in[11];
    const float* ln2_b   = (const float*)d_in[12];
    const float* cw1     = (const float*)d_in[13];
    const float* cb1     = (const float*)d_in[14];
    const float* cln1_g  = (const float*)d_in[15];
    const float* cln1_b  = (const float*)d_in[16];
    const float* cw2     = (const float*)d_in[17];
    const float* cb2     = (const float*)d_in[18];
    const float* cln2_g  = (const float*)d_in[19];
    const float* cln2_b  = (const float*)d_in[20];
    const float* cw3     = (const float*)d_in[21];
    const float* cb3     = (const float*)d_in[22];

    const int N = in_sizes[0] / 128;   // 50000
    const int E = in_sizes[1] / 2;     // 600000
    const int* esrc = eidx;
    const int* edst = eidx + E;

    const size_t HB = (size_t)N * 256;      // one bf16 [N,128] buffer, bytes
    char* base = (char*)d_ws;
    ushort_t* S0 = (ushort_t*)(base + 0 * HB);       // -> H0 (contig H base)
    ushort_t* S1 = (ushort_t*)(base + 1 * HB);       // -> H1
    ushort_t* S2 = (ushort_t*)(base + 2 * HB);       // -> H2
    ushort_t* X1 = (ushort_t*)(base + 3 * HB);       // x1 bf16
    ushort_t* AC = (ushort_t*)(base + 4 * HB);       // acc2 bf16
    char*     B3 = base + 5 * HB;                    // META

    int* rowptr  = (int*)B3;                      // N+1 (scan scratch)
    int* deg3    = rowptr + (N + 1);              // 3N
    int* cursor3 = deg3 + 3 * N;                  // 3N
    int* bsums   = cursor3 + 3 * N;               // 256
    int* btop    = bsums + 256;                   // 256
    int4* ranges = (int4*)(((uintptr_t)(btop + 256) + 15) & ~(uintptr_t)15);
    int* colidx  = (int*)(ranges + N);            // E
    ushort_t* wfb = (ushort_t*)(((uintptr_t)(colidx + E) + 255) & ~(uintptr_t)255);
    auto WSLOT = [&](int i) { return wfb + (size_t)i * 32768; };
    ushort_t* xh = (ushort_t*)(((uintptr_t)(wfb + 10 * 32768) + 255) & ~(uintptr_t)255);
    ushort_t* h2 = xh;                            // xh dead after conv1 gemm
    ushort_t* C1 = S0;                            // classifier temps reuse
    float*    C2 = (float*)S1;                    // [N,64] f32

    const dim3 blk(256);
    const int gGemm = (N + 63) / 64;
    const int gAgg  = (N + 7) / 8;
    const int gEdge = (E + 255) / 256;
    const int nScanB = (N + 255) / 256;
    const int gX2  = (N * 32 + 255) / 256;

    // ---------------- CSR build ----------------
    hipMemsetAsync(deg3, 0, (size_t)3 * N * sizeof(int), stream);
    hist3_kernel<<<gEdge, blk, 0, stream>>>(edst, etype, deg3, E);
    scan_deg3<<<nScanB, blk, 0, stream>>>(deg3, rowptr, bsums, N);
    scan_block<<<1, blk, 0, stream>>>(bsums, btop, nullptr, nScanB);
    scan_add_ranges<<<nScanB, blk, 0, stream>>>(rowptr, btop, deg3, ranges,
                                                cursor3, N);
    fill3_kernel<<<gEdge, blk, 0, stream>>>(esrc, edst, etype, cursor3, colidx, E);

    // ---------------- weights + x conversion (1 launch) ----------------
    convert_all_x2bf<<<76 + gX2, blk, 0, stream>>>(
        w1_root, w1_rel, w2_root, w2_rel, cw1, cw2, wfb, x, xh, N * 32);

    // ---------------- conv1 (add) ----------------
    agg3_add<<<gAgg, blk, 0, stream>>>(xh, ranges, colidx, S0, S1, S2, N);
    gemm_bf<128, 4, 1><<<gGemm, blk, 0, stream>>>(
        xh, S0, S1, S2, WSLOT(0), b1, ln1_g, ln1_b, X1, N);   // x1 bf16

    // ---------------- conv2 (max) ----------------
    gemm_conv2<<<gGemm, blk, 0, stream>>>(X1, wfb, b2, AC, S0, S1, S2, N);
    maxagg_ln<<<gAgg, blk, 0, stream>>>(S0, ranges, colidx, AC,
                                        X1, ln2_g, ln2_b, h2, N);

    // ---------------- classifier ----------------
    gemm_bf<128, 1, 2><<<gGemm, blk, 0, stream>>>(
        h2, h2, h2, h2, WSLOT(8), cb1, cln1_g, cln1_b, C1, N);   // bf16
    gemm_bf<64, 1, 3><<<gGemm, blk, 0, stream>>>(
        C1, C1, C1, C1, WSLOT(9), cb2, cln2_g, cln2_b, C2, N);   // f32 [N,64]
    gemm40_lsm<<<gGemm, blk, 0, stream>>>(C2, cw3, cb3, (float*)d_out, N);
}